// Round 3
// baseline (315.584 us; speedup 1.0000x reference)
//
#include <hip/hip_runtime.h>
#include <hip/hip_bf16.h>

// EdgeConv: N=16384 points, C=64, D=64, K=16 neighbors. All I/O fp32.
// Pipeline:
//   1) knn_kernel : exact 16-NN per point (fp32 distances, LDS-staged pos)
//   2) prep_kernel: v = x@(W1a-W1b)+b1 -> d_out (fp32, block-local reuse only)
//                   u = x@W1b          -> ws   (bf16, gathered by neighbor)
//   3) edge_kernel: h = relu(v_i + u_j); out = max_k(h @ W2) + b2
// ws usage: knn ushort 512KB @0, u bf16 2MB @512KB  (total 2.5MB -- round-2
// failure was ws overflow corrupting the harness's pristine input copies).

#define NPTS 16384
#define CH 64

typedef __attribute__((ext_vector_type(8))) short short8;
typedef __attribute__((ext_vector_type(4))) float floatx4;

__device__ __forceinline__ unsigned short f2bf(float f) {
    unsigned u = __float_as_uint(f);
    u += 0x7FFFu + ((u >> 16) & 1u);   // RNE
    return (unsigned short)(u >> 16);
}
__device__ __forceinline__ float bf2f(unsigned short u) {
    return __uint_as_float(((unsigned)u) << 16);
}

// ---------------------------------------------------------------------------
// KNN. Block = 256 thr = 4 waves, each wave owns 4 rows. pos staged in LDS
// SoA chunks of 2048 points (32 KB). Top-16 = distributed sorted u64 keys
// (monotone float bits << 32 | idx) in lanes 0..15; exact set + index ties.
// ---------------------------------------------------------------------------
__device__ __forceinline__ void topk_insert(unsigned long long& list,
                                            unsigned long long& tau,
                                            unsigned long long mask,
                                            unsigned long long pk,
                                            int lane) {
    while (mask) {
        const int src = __ffsll(mask) - 1;
        mask &= mask - 1;
        const unsigned long long v = __shfl(pk, src);
        const unsigned long long prev = __shfl_up(list, 1);
        const bool keep = (list < v);
        const bool pvlt = (lane == 0) ? true : (prev < v);
        list = keep ? list : (pvlt ? v : prev);
    }
    tau = __shfl(list, 15);
}

#define CHUNK 2048

__global__ __launch_bounds__(256) void knn_kernel(const float* __restrict__ pos,
                                                  unsigned short* __restrict__ knn_out) {
    __shared__ float sx[CHUNK], sy[CHUNK], sz[CHUNK], ssq[CHUNK];
    const int t    = threadIdx.x;
    const int lane = t & 63;
    const int w    = t >> 6;
    const int row0 = blockIdx.x * 16 + w * 4;   // wave's 4 rows

    float xi[4], yi[4], zi[4], sqi[4];
#pragma unroll
    for (int r = 0; r < 4; ++r) {
        xi[r]  = pos[(row0 + r) * 3 + 0];
        yi[r]  = pos[(row0 + r) * 3 + 1];
        zi[r]  = pos[(row0 + r) * 3 + 2];
        sqi[r] = xi[r] * xi[r] + yi[r] * yi[r] + zi[r] * zi[r];
    }

    unsigned long long list[4] = {~0ULL, ~0ULL, ~0ULL, ~0ULL};
    unsigned long long tau[4]  = {~0ULL, ~0ULL, ~0ULL, ~0ULL};

    for (int c0 = 0; c0 < NPTS; c0 += CHUNK) {
        __syncthreads();   // previous chunk's readers done
        for (int i = t; i < CHUNK; i += 256) {
            const int j = c0 + i;
            const float a = pos[j * 3 + 0];
            const float b = pos[j * 3 + 1];
            const float c = pos[j * 3 + 2];
            sx[i] = a; sy[i] = b; sz[i] = c;
            ssq[i] = a * a + b * b + c * c;
        }
        __syncthreads();

        for (int it = 0; it < CHUNK; it += 64) {
            const int i = it + lane;
            const int j = c0 + i;
            const float xj = sx[i], yj = sy[i], zj = sz[i], sqj = ssq[i];
#pragma unroll
            for (int r = 0; r < 4; ++r) {
                const float dot = xi[r] * xj + yi[r] * yj + zi[r] * zj;
                const float d = (sqi[r] + sqj) - 2.0f * dot;
                unsigned key = __float_as_uint(d);
                key = ((int)key < 0) ? ~key : (key | 0x80000000u);  // monotone
                const unsigned long long pk =
                    (((unsigned long long)key) << 32) | (unsigned)j;
                const bool cand = (j != row0 + r) && (pk < tau[r]);
                const unsigned long long mask = __ballot(cand);
                if (mask) topk_insert(list[r], tau[r], mask, pk, lane);
            }
        }
    }
#pragma unroll
    for (int r = 0; r < 4; ++r)
        if (lane < 16)
            knn_out[(row0 + r) * 16 + lane] =
                (unsigned short)(unsigned)(list[r] & 0xFFFFULL);
}

// ---------------------------------------------------------------------------
// prep: v_p = x_p@(W1a - W1b) + b1 -> vout (fp32, == d_out)
//       u_p = x_p@W1b              -> ubuf (bf16)
// Block = 64 points. bf16 MFMA 16x16x32, fp32 accumulate.
// ---------------------------------------------------------------------------
__global__ __launch_bounds__(256) void prep_kernel(const float* __restrict__ x,
                                                   const float* __restrict__ W1,
                                                   const float* __restrict__ b1,
                                                   float* __restrict__ vout,
                                                   unsigned short* __restrict__ ubuf) {
    __shared__ unsigned short Wct[128 * 72];  // [n][k] bf16, n<64: (W1a-W1b) col, else W1b
    __shared__ unsigned short Abuf[64 * 72];  // x tile bf16 [row][k]
    __shared__ float Wraw[128 * 64];          // raw W1 fp32

    const int t    = threadIdx.x;
    const int lane = t & 63;
    const int w    = t >> 6;

    {   // coalesced W1 load
        const float4* W1v = (const float4*)W1;   // 2048 float4
        float4* Wr4 = (float4*)Wraw;
#pragma unroll
        for (int i = 0; i < 8; ++i) Wr4[i * 256 + t] = W1v[i * 256 + t];
    }
    __syncthreads();
    {   // build Wct[n][k]
        const int n = t & 127;
        const int ks = (t >> 7) * 32;
#pragma unroll
        for (int i = 0; i < 32; ++i) {
            const int k = ks + i;
            float val;
            if (n < 64) val = Wraw[k * 64 + n] - Wraw[(64 + k) * 64 + n];
            else        val = Wraw[(64 + k) * 64 + (n - 64)];
            Wct[n * 72 + k] = f2bf(val);
        }
    }
    {   // stage x tile -> bf16
        const int col = t & 63;
#pragma unroll
        for (int i = 0; i < 16; ++i) {
            const int row = (t >> 6) + 4 * i;
            const int gp = blockIdx.x * 64 + row;
            Abuf[row * 72 + col] = f2bf(x[(size_t)gp * CH + col]);
        }
    }
    __syncthreads();

    const int m16 = lane & 15;
    const int q   = lane >> 4;

    floatx4 acc[8];
#pragma unroll
    for (int nt = 0; nt < 8; ++nt) acc[nt] = (floatx4){0.f, 0.f, 0.f, 0.f};

#pragma unroll
    for (int kk = 0; kk < 64; kk += 32) {
        const short8 a = *(const short8*)(Abuf + (w * 16 + m16) * 72 + kk + q * 8);
#pragma unroll
        for (int nt = 0; nt < 8; ++nt) {
            const short8 b = *(const short8*)(Wct + (nt * 16 + m16) * 72 + kk + q * 8);
            acc[nt] = __builtin_amdgcn_mfma_f32_16x16x32_bf16(a, b, acc[nt], 0, 0, 0);
        }
    }

#pragma unroll
    for (int nt = 0; nt < 8; ++nt) {
        const int n = nt * 16 + m16;
#pragma unroll
        for (int r = 0; r < 4; ++r) {
            const int gp = blockIdx.x * 64 + w * 16 + q * 4 + r;
            if (n < 64) vout[(size_t)gp * CH + n] = acc[nt][r] + b1[n];
            else        ubuf[(size_t)gp * CH + (n - 64)] = f2bf(acc[nt][r]);
        }
    }
}

// ---------------------------------------------------------------------------
// edge: block = 8 points (128 edge rows). h = relu(v_i + u_j) staged bf16 in
// LDS; GEMM2 (128x64)@(64x64) via MFMA; max over each point's 16 rows; +b2.
// v_i lives in out[] (written by prep; only this block reads its own rows,
// and overwrites them only after consuming them -> no cross-block hazard).
// ---------------------------------------------------------------------------
__global__ __launch_bounds__(256) void edge_kernel(const unsigned short* __restrict__ ubuf,
                                                   const float* __restrict__ W2,
                                                   const float* __restrict__ b2,
                                                   const unsigned short* __restrict__ knn,
                                                   float* __restrict__ out) {
    __shared__ unsigned short h[128 * 72];    // edge-row tile bf16
    __shared__ unsigned short W2t[64 * 72];   // [e][d] bf16

    const int t    = threadIdx.x;
    const int lane = t & 63;
    const int w    = t >> 6;

    {   // W2^T -> bf16 LDS
        const int n = t & 63;
        const int kb = (t >> 6) * 16;
#pragma unroll
        for (int i = 0; i < 16; ++i) {
            const int k = kb + i;
            W2t[n * 72 + k] = f2bf(W2[k * 64 + n]);
        }
    }
    {   // h rows: iteration i handles point i of this block
        const int k = t >> 4;       // neighbor slot 0..15
        const int c = t & 15;       // 4-element chunk 0..15
#pragma unroll
        for (int i = 0; i < 8; ++i) {
            const int gn = blockIdx.x * 8 + i;
            const int gj = (int)knn[gn * 16 + k];
            const float4  vv = ((const float4*)(out + (size_t)gn * CH))[c];
            const ushort4 uu = ((const ushort4*)(ubuf + (size_t)gj * CH))[c];
            ushort4 hv;
            hv.x = f2bf(fmaxf(vv.x + bf2f(uu.x), 0.f));
            hv.y = f2bf(fmaxf(vv.y + bf2f(uu.y), 0.f));
            hv.z = f2bf(fmaxf(vv.z + bf2f(uu.z), 0.f));
            hv.w = f2bf(fmaxf(vv.w + bf2f(uu.w), 0.f));
            const int row = i * 16 + k;
            *(ushort4*)(h + row * 72 + c * 4) = hv;
        }
    }
    __syncthreads();

    const int m16 = lane & 15;
    const int q   = lane >> 4;

    floatx4 acc[2][4];
#pragma unroll
    for (int i = 0; i < 2; ++i)
#pragma unroll
        for (int nt = 0; nt < 4; ++nt) acc[i][nt] = (floatx4){0.f, 0.f, 0.f, 0.f};

#pragma unroll
    for (int kk = 0; kk < 64; kk += 32) {
        const short8 a0 = *(const short8*)(h + ((w * 2 + 0) * 16 + m16) * 72 + kk + q * 8);
        const short8 a1 = *(const short8*)(h + ((w * 2 + 1) * 16 + m16) * 72 + kk + q * 8);
#pragma unroll
        for (int nt = 0; nt < 4; ++nt) {
            const short8 b = *(const short8*)(W2t + (nt * 16 + m16) * 72 + kk + q * 8);
            acc[0][nt] = __builtin_amdgcn_mfma_f32_16x16x32_bf16(a0, b, acc[0][nt], 0, 0, 0);
            acc[1][nt] = __builtin_amdgcn_mfma_f32_16x16x32_bf16(a1, b, acc[1][nt], 0, 0, 0);
        }
    }

    // max over the 16 rows of each point's m-tile, +b2, store fp32
#pragma unroll
    for (int i = 0; i < 2; ++i) {
        const int mt = w * 2 + i;
        const int gn = blockIdx.x * 8 + mt;
#pragma unroll
        for (int nt = 0; nt < 4; ++nt) {
            float m0 = fmaxf(fmaxf(acc[i][nt][0], acc[i][nt][1]),
                             fmaxf(acc[i][nt][2], acc[i][nt][3]));
            m0 = fmaxf(m0, __shfl_xor(m0, 16));
            m0 = fmaxf(m0, __shfl_xor(m0, 32));
            if (lane < 16)
                out[(size_t)gn * CH + nt * 16 + lane] = m0 + b2[nt * 16 + lane];
        }
    }
}

extern "C" void kernel_launch(void* const* d_in, const int* in_sizes, int n_in,
                              void* d_out, int out_size, void* d_ws, size_t ws_size,
                              hipStream_t stream) {
    const float* x   = (const float*)d_in[0];
    const float* pos = (const float*)d_in[1];
    const float* W1  = (const float*)d_in[2];
    const float* b1  = (const float*)d_in[3];
    const float* W2  = (const float*)d_in[4];
    const float* b2  = (const float*)d_in[5];
    float* out = (float*)d_out;

    unsigned short* knn  = (unsigned short*)d_ws;               // 512 KB
    unsigned short* ubuf = (unsigned short*)((char*)d_ws + (size_t)NPTS * 16 * 2);  // 2 MB

    knn_kernel<<<NPTS / 16, 256, 0, stream>>>(pos, knn);
    prep_kernel<<<NPTS / 64, 256, 0, stream>>>(x, W1, b1, out, ubuf);
    edge_kernel<<<NPTS / 8, 256, 0, stream>>>(ubuf, W2, b2, knn, out);
}

// Round 4
// 295.071 us; speedup vs baseline: 1.0695x; 1.0695x over previous
//
#include <hip/hip_runtime.h>
#include <hip/hip_bf16.h>

// EdgeConv: N=16384 points, C=64, D=64, K=16 neighbors. All I/O fp32.
// Pipeline:
//   1) knn_kernel : exact 16-NN per point (fp32 distances, LDS-staged pos)
//   2) prep_kernel: v = x@(W1a-W1b)+b1 -> d_out (fp32, block-local reuse only)
//                   u = x@W1b          -> ws   (bf16, gathered by neighbor)
//   3) edge_kernel: h = relu(v_i + u_j); out = max_k(h @ W2) + b2
// ws usage: knn ushort 512KB @0, u bf16 2MB @512KB (total 2.5MB).
// R4: slim knn inner loop -- float screen (cmp IS the ballot), u64 key built
// only on insert events, readlane broadcast instead of ds_bpermute, float4 LDS.

#define NPTS 16384
#define CH 64

typedef __attribute__((ext_vector_type(8))) short short8;
typedef __attribute__((ext_vector_type(4))) float floatx4;

__device__ __forceinline__ unsigned short f2bf(float f) {
    unsigned u = __float_as_uint(f);
    u += 0x7FFFu + ((u >> 16) & 1u);   // RNE
    return (unsigned short)(u >> 16);
}
__device__ __forceinline__ float bf2f(unsigned short u) {
    return __uint_as_float(((unsigned)u) << 16);
}

// ---------------------------------------------------------------------------
// KNN. Block = 256 thr = 4 waves, each wave owns 4 rows. pos staged in LDS
// as float4{x,y,z,sq} chunks of 2048 (32 KB). Top-16 = distributed sorted
// u64 keys (monotone float bits << 32 | idx) in lanes 0..15.
// Common path per row-candidate: 3 fma + add + fma + 1 float cmp (=ballot).
// Key construction + sorted insert only on events (~127/row over the sweep).
// Sentinel key hi = 0xFF800000 (=key(+inf)) so tau unpack yields +INF.
// ---------------------------------------------------------------------------
#define CHUNK 2048

__global__ __launch_bounds__(256) void knn_kernel(const float* __restrict__ pos,
                                                  unsigned short* __restrict__ knn_out) {
    __shared__ float4 sp[CHUNK];
    const int t    = threadIdx.x;
    const int lane = t & 63;
    const int w    = t >> 6;
    const int row0 = blockIdx.x * 16 + w * 4;   // wave's 4 rows

    float xi[4], yi[4], zi[4], sqi[4];
#pragma unroll
    for (int r = 0; r < 4; ++r) {
        xi[r]  = pos[(row0 + r) * 3 + 0];
        yi[r]  = pos[(row0 + r) * 3 + 1];
        zi[r]  = pos[(row0 + r) * 3 + 2];
        sqi[r] = xi[r] * xi[r] + yi[r] * yi[r] + zi[r] * zi[r];
    }

    unsigned long long list[4];
    float tau[4];
#pragma unroll
    for (int r = 0; r < 4; ++r) {
        list[r] = 0xFF800000FFFFFFFFULL;   // key(+inf) | idx 0xFFFFFFFF
        tau[r]  = __uint_as_float(0x7F800000u);   // +INF
    }

    for (int c0 = 0; c0 < NPTS; c0 += CHUNK) {
        __syncthreads();   // previous chunk's readers done
        for (int i = t; i < CHUNK; i += 256) {
            const int j = c0 + i;
            const float a = pos[j * 3 + 0];
            const float b = pos[j * 3 + 1];
            const float c = pos[j * 3 + 2];
            sp[i] = make_float4(a, b, c, a * a + b * b + c * c);
        }
        __syncthreads();

        for (int it = 0; it < CHUNK; it += 64) {
            const float4 p = sp[it + lane];
            const int base = c0 + it;
#pragma unroll
            for (int r = 0; r < 4; ++r) {
                const float dot = fmaf(xi[r], p.x, fmaf(yi[r], p.y, zi[r] * p.z));
                const float d   = fmaf(-2.0f, dot, sqi[r] + p.w);
                unsigned long long mask = __ballot(d <= tau[r]);
                if (mask) {
                    const int row = row0 + r;
                    if ((unsigned)(row - base) < 64u)
                        mask &= ~(1ULL << (row - base));   // drop self
                    if (mask) {
                        // build per-lane key only now (event path)
                        unsigned kd = __float_as_uint(d);
                        kd = ((int)kd < 0) ? ~kd : (kd | 0x80000000u);  // monotone
                        const unsigned klo = (unsigned)(base + lane);
                        do {
                            const int src = __ffsll(mask) - 1;
                            mask &= mask - 1;
                            const unsigned slo = (unsigned)__builtin_amdgcn_readlane((int)klo, src);
                            const unsigned shi = (unsigned)__builtin_amdgcn_readlane((int)kd, src);
                            const unsigned long long v =
                                (((unsigned long long)shi) << 32) | slo;
                            unsigned long long prev = __shfl_up(list[r], 1);
                            if (lane == 0) prev = 0ULL;
                            const unsigned long long lr = list[r];
                            list[r] = (lr < v) ? lr : ((prev < v) ? v : prev);
                        } while (mask);
                        // tau = float of list[15]'s distance bits
                        const unsigned thi = (unsigned)__builtin_amdgcn_readlane(
                            (int)(unsigned)(list[r] >> 32), 15);
                        const unsigned fb =
                            (thi >= 0x80000000u) ? (thi & 0x7FFFFFFFu) : ~thi;
                        tau[r] = __uint_as_float(fb);
                    }
                }
            }
        }
    }
#pragma unroll
    for (int r = 0; r < 4; ++r)
        if (lane < 16)
            knn_out[(row0 + r) * 16 + lane] =
                (unsigned short)(unsigned)(list[r] & 0xFFFFULL);
}

// ---------------------------------------------------------------------------
// prep: v_p = x_p@(W1a - W1b) + b1 -> vout (fp32, == d_out)
//       u_p = x_p@W1b              -> ubuf (bf16)
// Block = 64 points. bf16 MFMA 16x16x32, fp32 accumulate.
// ---------------------------------------------------------------------------
__global__ __launch_bounds__(256) void prep_kernel(const float* __restrict__ x,
                                                   const float* __restrict__ W1,
                                                   const float* __restrict__ b1,
                                                   float* __restrict__ vout,
                                                   unsigned short* __restrict__ ubuf) {
    __shared__ unsigned short Wct[128 * 72];  // [n][k] bf16, n<64: (W1a-W1b) col, else W1b
    __shared__ unsigned short Abuf[64 * 72];  // x tile bf16 [row][k]
    __shared__ float Wraw[128 * 64];          // raw W1 fp32

    const int t    = threadIdx.x;
    const int lane = t & 63;
    const int w    = t >> 6;

    {   // coalesced W1 load
        const float4* W1v = (const float4*)W1;   // 2048 float4
        float4* Wr4 = (float4*)Wraw;
#pragma unroll
        for (int i = 0; i < 8; ++i) Wr4[i * 256 + t] = W1v[i * 256 + t];
    }
    __syncthreads();
    {   // build Wct[n][k]
        const int n = t & 127;
        const int ks = (t >> 7) * 32;
#pragma unroll
        for (int i = 0; i < 32; ++i) {
            const int k = ks + i;
            float val;
            if (n < 64) val = Wraw[k * 64 + n] - Wraw[(64 + k) * 64 + n];
            else        val = Wraw[(64 + k) * 64 + (n - 64)];
            Wct[n * 72 + k] = f2bf(val);
        }
    }
    {   // stage x tile -> bf16
        const int col = t & 63;
#pragma unroll
        for (int i = 0; i < 16; ++i) {
            const int row = (t >> 6) + 4 * i;
            const int gp = blockIdx.x * 64 + row;
            Abuf[row * 72 + col] = f2bf(x[(size_t)gp * CH + col]);
        }
    }
    __syncthreads();

    const int m16 = lane & 15;
    const int q   = lane >> 4;

    floatx4 acc[8];
#pragma unroll
    for (int nt = 0; nt < 8; ++nt) acc[nt] = (floatx4){0.f, 0.f, 0.f, 0.f};

#pragma unroll
    for (int kk = 0; kk < 64; kk += 32) {
        const short8 a = *(const short8*)(Abuf + (w * 16 + m16) * 72 + kk + q * 8);
#pragma unroll
        for (int nt = 0; nt < 8; ++nt) {
            const short8 b = *(const short8*)(Wct + (nt * 16 + m16) * 72 + kk + q * 8);
            acc[nt] = __builtin_amdgcn_mfma_f32_16x16x32_bf16(a, b, acc[nt], 0, 0, 0);
        }
    }

#pragma unroll
    for (int nt = 0; nt < 8; ++nt) {
        const int n = nt * 16 + m16;
#pragma unroll
        for (int r = 0; r < 4; ++r) {
            const int gp = blockIdx.x * 64 + w * 16 + q * 4 + r;
            if (n < 64) vout[(size_t)gp * CH + n] = acc[nt][r] + b1[n];
            else        ubuf[(size_t)gp * CH + (n - 64)] = f2bf(acc[nt][r]);
        }
    }
}

// ---------------------------------------------------------------------------
// edge: block = 8 points (128 edge rows). h = relu(v_i + u_j) staged bf16 in
// LDS; GEMM2 (128x64)@(64x64) via MFMA; max over each point's 16 rows; +b2.
// v_i lives in out[] (written by prep; only this block reads its own rows,
// and overwrites them only after consuming them -> no cross-block hazard).
// ---------------------------------------------------------------------------
__global__ __launch_bounds__(256) void edge_kernel(const unsigned short* __restrict__ ubuf,
                                                   const float* __restrict__ W2,
                                                   const float* __restrict__ b2,
                                                   const unsigned short* __restrict__ knn,
                                                   float* __restrict__ out) {
    __shared__ unsigned short h[128 * 72];    // edge-row tile bf16
    __shared__ unsigned short W2t[64 * 72];   // [e][d] bf16

    const int t    = threadIdx.x;
    const int lane = t & 63;
    const int w    = t >> 6;

    {   // W2^T -> bf16 LDS
        const int n = t & 63;
        const int kb = (t >> 6) * 16;
#pragma unroll
        for (int i = 0; i < 16; ++i) {
            const int k = kb + i;
            W2t[n * 72 + k] = f2bf(W2[k * 64 + n]);
        }
    }
    {   // h rows: iteration i handles point i of this block
        const int k = t >> 4;       // neighbor slot 0..15
        const int c = t & 15;       // 4-element chunk 0..15
#pragma unroll
        for (int i = 0; i < 8; ++i) {
            const int gn = blockIdx.x * 8 + i;
            const int gj = (int)knn[gn * 16 + k];
            const float4  vv = ((const float4*)(out + (size_t)gn * CH))[c];
            const ushort4 uu = ((const ushort4*)(ubuf + (size_t)gj * CH))[c];
            ushort4 hv;
            hv.x = f2bf(fmaxf(vv.x + bf2f(uu.x), 0.f));
            hv.y = f2bf(fmaxf(vv.y + bf2f(uu.y), 0.f));
            hv.z = f2bf(fmaxf(vv.z + bf2f(uu.z), 0.f));
            hv.w = f2bf(fmaxf(vv.w + bf2f(uu.w), 0.f));
            const int row = i * 16 + k;
            *(ushort4*)(h + row * 72 + c * 4) = hv;
        }
    }
    __syncthreads();

    const int m16 = lane & 15;
    const int q   = lane >> 4;

    floatx4 acc[2][4];
#pragma unroll
    for (int i = 0; i < 2; ++i)
#pragma unroll
        for (int nt = 0; nt < 4; ++nt) acc[i][nt] = (floatx4){0.f, 0.f, 0.f, 0.f};

#pragma unroll
    for (int kk = 0; kk < 64; kk += 32) {
        const short8 a0 = *(const short8*)(h + ((w * 2 + 0) * 16 + m16) * 72 + kk + q * 8);
        const short8 a1 = *(const short8*)(h + ((w * 2 + 1) * 16 + m16) * 72 + kk + q * 8);
#pragma unroll
        for (int nt = 0; nt < 4; ++nt) {
            const short8 b = *(const short8*)(W2t + (nt * 16 + m16) * 72 + kk + q * 8);
            acc[0][nt] = __builtin_amdgcn_mfma_f32_16x16x32_bf16(a0, b, acc[0][nt], 0, 0, 0);
            acc[1][nt] = __builtin_amdgcn_mfma_f32_16x16x32_bf16(a1, b, acc[1][nt], 0, 0, 0);
        }
    }

    // max over the 16 rows of each point's m-tile, +b2, store fp32
#pragma unroll
    for (int i = 0; i < 2; ++i) {
        const int mt = w * 2 + i;
        const int gn = blockIdx.x * 8 + mt;
#pragma unroll
        for (int nt = 0; nt < 4; ++nt) {
            float m0 = fmaxf(fmaxf(acc[i][nt][0], acc[i][nt][1]),
                             fmaxf(acc[i][nt][2], acc[i][nt][3]));
            m0 = fmaxf(m0, __shfl_xor(m0, 16));
            m0 = fmaxf(m0, __shfl_xor(m0, 32));
            if (lane < 16)
                out[(size_t)gn * CH + nt * 16 + lane] = m0 + b2[nt * 16 + lane];
        }
    }
}

extern "C" void kernel_launch(void* const* d_in, const int* in_sizes, int n_in,
                              void* d_out, int out_size, void* d_ws, size_t ws_size,
                              hipStream_t stream) {
    const float* x   = (const float*)d_in[0];
    const float* pos = (const float*)d_in[1];
    const float* W1  = (const float*)d_in[2];
    const float* b1  = (const float*)d_in[3];
    const float* W2  = (const float*)d_in[4];
    const float* b2  = (const float*)d_in[5];
    float* out = (float*)d_out;

    unsigned short* knn  = (unsigned short*)d_ws;               // 512 KB
    unsigned short* ubuf = (unsigned short*)((char*)d_ws + (size_t)NPTS * 16 * 2);  // 2 MB

    knn_kernel<<<NPTS / 16, 256, 0, stream>>>(pos, knn);
    prep_kernel<<<NPTS / 64, 256, 0, stream>>>(x, W1, b1, out, ubuf);
    edge_kernel<<<NPTS / 8, 256, 0, stream>>>(ubuf, W2, b2, knn, out);
}

// Round 5
// 248.368 us; speedup vs baseline: 1.2706x; 1.1880x over previous
//
#include <hip/hip_runtime.h>
#include <hip/hip_bf16.h>

// EdgeConv: N=16384 points, C=64, D=64, K=16 neighbors. All I/O fp32.
// Pipeline:
//   1) knn_kernel : exact 16-NN per point (fp32 distances, LDS-staged pos)
//   2) prep_kernel: v = x@(W1a-W1b)+b1 -> d_out (fp32, block-local reuse only)
//                   u = x@W1b          -> ws   (bf16, gathered by neighbor)
//   3) edge_kernel: h = relu(v_i + u_j); out = max_k(h @ W2) + b2
// ws usage: knn ushort 512KB @0, u bf16 2MB @512KB (total 2.5MB).
// R5: kill the knn cold-start flood (warm-start top-16 via 64-lane bitonic
// sort of the first batch -> tau tight immediately) + DPP row_shr:1 shift
// instead of 64-bit __shfl_up (ds_permute) in the insert loop.

#define NPTS 16384
#define CH 64

typedef __attribute__((ext_vector_type(8))) short short8;
typedef __attribute__((ext_vector_type(4))) float floatx4;

__device__ __forceinline__ unsigned short f2bf(float f) {
    unsigned u = __float_as_uint(f);
    u += 0x7FFFu + ((u >> 16) & 1u);   // RNE
    return (unsigned short)(u >> 16);
}
__device__ __forceinline__ float bf2f(unsigned short u) {
    return __uint_as_float(((unsigned)u) << 16);
}

// 64-bit DPP row_shr:1 (shift within 16-lane DPP rows; lanes 0/16/32/48 get 0).
// Our sorted list lives in lanes 0..15, so this is exactly shfl_up-by-1 there.
__device__ __forceinline__ unsigned long long dpp_shr1_u64(unsigned long long x) {
    int lo = (int)(unsigned)(x & 0xFFFFFFFFULL);
    int hi = (int)(unsigned)(x >> 32);
    lo = __builtin_amdgcn_update_dpp(0, lo, 0x111, 0xF, 0xF, false);
    hi = __builtin_amdgcn_update_dpp(0, hi, 0x111, 0xF, 0xF, false);
    return (((unsigned long long)(unsigned)hi) << 32) | (unsigned)lo;
}

// ---------------------------------------------------------------------------
// KNN. Block = 256 thr = 4 waves, each wave owns 4 rows. pos staged in LDS
// as float4{x,y,z,sq} chunks of 2048 (32 KB). Top-16 = distributed sorted
// u64 keys (monotone float bits << 32 | idx) in lanes 0..15.
// Warm start: bitonic-sort the first 64 candidates' keys -> exact initial
// top-16 + finite tau, eliminating the tau=+inf insert flood.
// ---------------------------------------------------------------------------
#define CHUNK 2048
#define SENT 0xFF800000FFFFFFFFULL   // key(+inf) | idx-all-ones

__global__ __launch_bounds__(256) void knn_kernel(const float* __restrict__ pos,
                                                  unsigned short* __restrict__ knn_out) {
    __shared__ float4 sp[CHUNK];
    const int t    = threadIdx.x;
    const int lane = t & 63;
    const int w    = t >> 6;
    const int row0 = blockIdx.x * 16 + w * 4;   // wave's 4 rows

    float xi[4], yi[4], zi[4], sqi[4];
#pragma unroll
    for (int r = 0; r < 4; ++r) {
        xi[r]  = pos[(row0 + r) * 3 + 0];
        yi[r]  = pos[(row0 + r) * 3 + 1];
        zi[r]  = pos[(row0 + r) * 3 + 2];
        sqi[r] = xi[r] * xi[r] + yi[r] * yi[r] + zi[r] * zi[r];
    }

    unsigned long long list[4];
    float tau[4];

    for (int c0 = 0; c0 < NPTS; c0 += CHUNK) {
        __syncthreads();   // previous chunk's readers done
        for (int i = t; i < CHUNK; i += 256) {
            const int j = c0 + i;
            const float a = pos[j * 3 + 0];
            const float b = pos[j * 3 + 1];
            const float c = pos[j * 3 + 2];
            sp[i] = make_float4(a, b, c, a * a + b * b + c * c);
        }
        __syncthreads();

        int it0 = 0;
        if (c0 == 0) {
            // ---- warm start: exact top-16 of candidates 0..63 via bitonic sort
            const float4 p = sp[lane];
#pragma unroll
            for (int r = 0; r < 4; ++r) {
                const float dot = fmaf(xi[r], p.x, fmaf(yi[r], p.y, zi[r] * p.z));
                const float d   = fmaf(-2.0f, dot, sqi[r] + p.w);
                unsigned kd = __float_as_uint(d);
                kd = ((int)kd < 0) ? ~kd : (kd | 0x80000000u);
                unsigned long long key =
                    (((unsigned long long)kd) << 32) | (unsigned)lane;
                if (lane == row0 + r) key = SENT;   // self-exclusion
                // 64-lane bitonic sort, ascending by lane
#pragma unroll
                for (int k = 2; k <= 64; k <<= 1) {
#pragma unroll
                    for (int j = k >> 1; j >= 1; j >>= 1) {
                        const unsigned long long o = __shfl_xor(key, j);
                        const bool takeMin =
                            (((lane & k) == 0) == ((lane & j) == 0));
                        const unsigned long long mn = (key < o) ? key : o;
                        const unsigned long long mx = (key < o) ? o : key;
                        key = takeMin ? mn : mx;
                    }
                }
                list[r] = key;   // lanes 0..15 = smallest 16, sorted
                const unsigned thi = (unsigned)__builtin_amdgcn_readlane(
                    (int)(unsigned)(key >> 32), 15);
                const unsigned fb =
                    (thi >= 0x80000000u) ? (thi & 0x7FFFFFFFu) : ~thi;
                tau[r] = __uint_as_float(fb);
            }
            it0 = 64;
        }

        for (int it = it0; it < CHUNK; it += 64) {
            const float4 p = sp[it + lane];
            const int base = c0 + it;
#pragma unroll
            for (int r = 0; r < 4; ++r) {
                const float dot = fmaf(xi[r], p.x, fmaf(yi[r], p.y, zi[r] * p.z));
                const float d   = fmaf(-2.0f, dot, sqi[r] + p.w);
                unsigned long long mask = __ballot(d <= tau[r]);
                if (mask) {
                    const int row = row0 + r;
                    if ((unsigned)(row - base) < 64u)
                        mask &= ~(1ULL << (row - base));   // drop self
                    if (mask) {
                        // event path: build key only now
                        unsigned kd = __float_as_uint(d);
                        kd = ((int)kd < 0) ? ~kd : (kd | 0x80000000u);
                        const unsigned klo = (unsigned)(base + lane);
                        do {
                            const int src = __ffsll(mask) - 1;
                            mask &= mask - 1;
                            const unsigned slo = (unsigned)__builtin_amdgcn_readlane((int)klo, src);
                            const unsigned shi = (unsigned)__builtin_amdgcn_readlane((int)kd, src);
                            const unsigned long long v =
                                (((unsigned long long)shi) << 32) | slo;
                            const unsigned long long prev = dpp_shr1_u64(list[r]);
                            const unsigned long long lr = list[r];
                            list[r] = (lr < v) ? lr : ((prev < v) ? v : prev);
                        } while (mask);
                        // tau = float of list[15]'s distance bits
                        const unsigned thi = (unsigned)__builtin_amdgcn_readlane(
                            (int)(unsigned)(list[r] >> 32), 15);
                        const unsigned fb =
                            (thi >= 0x80000000u) ? (thi & 0x7FFFFFFFu) : ~thi;
                        tau[r] = __uint_as_float(fb);
                    }
                }
            }
        }
    }
#pragma unroll
    for (int r = 0; r < 4; ++r)
        if (lane < 16)
            knn_out[(row0 + r) * 16 + lane] =
                (unsigned short)(unsigned)(list[r] & 0xFFFFULL);
}

// ---------------------------------------------------------------------------
// prep: v_p = x_p@(W1a - W1b) + b1 -> vout (fp32, == d_out)
//       u_p = x_p@W1b              -> ubuf (bf16)
// Block = 64 points. bf16 MFMA 16x16x32, fp32 accumulate.
// ---------------------------------------------------------------------------
__global__ __launch_bounds__(256) void prep_kernel(const float* __restrict__ x,
                                                   const float* __restrict__ W1,
                                                   const float* __restrict__ b1,
                                                   float* __restrict__ vout,
                                                   unsigned short* __restrict__ ubuf) {
    __shared__ unsigned short Wct[128 * 72];  // [n][k] bf16, n<64: (W1a-W1b) col, else W1b
    __shared__ unsigned short Abuf[64 * 72];  // x tile bf16 [row][k]
    __shared__ float Wraw[128 * 64];          // raw W1 fp32

    const int t    = threadIdx.x;
    const int lane = t & 63;
    const int w    = t >> 6;

    {   // coalesced W1 load
        const float4* W1v = (const float4*)W1;   // 2048 float4
        float4* Wr4 = (float4*)Wraw;
#pragma unroll
        for (int i = 0; i < 8; ++i) Wr4[i * 256 + t] = W1v[i * 256 + t];
    }
    __syncthreads();
    {   // build Wct[n][k]
        const int n = t & 127;
        const int ks = (t >> 7) * 32;
#pragma unroll
        for (int i = 0; i < 32; ++i) {
            const int k = ks + i;
            float val;
            if (n < 64) val = Wraw[k * 64 + n] - Wraw[(64 + k) * 64 + n];
            else        val = Wraw[(64 + k) * 64 + (n - 64)];
            Wct[n * 72 + k] = f2bf(val);
        }
    }
    {   // stage x tile -> bf16
        const int col = t & 63;
#pragma unroll
        for (int i = 0; i < 16; ++i) {
            const int row = (t >> 6) + 4 * i;
            const int gp = blockIdx.x * 64 + row;
            Abuf[row * 72 + col] = f2bf(x[(size_t)gp * CH + col]);
        }
    }
    __syncthreads();

    const int m16 = lane & 15;
    const int q   = lane >> 4;

    floatx4 acc[8];
#pragma unroll
    for (int nt = 0; nt < 8; ++nt) acc[nt] = (floatx4){0.f, 0.f, 0.f, 0.f};

#pragma unroll
    for (int kk = 0; kk < 64; kk += 32) {
        const short8 a = *(const short8*)(Abuf + (w * 16 + m16) * 72 + kk + q * 8);
#pragma unroll
        for (int nt = 0; nt < 8; ++nt) {
            const short8 b = *(const short8*)(Wct + (nt * 16 + m16) * 72 + kk + q * 8);
            acc[nt] = __builtin_amdgcn_mfma_f32_16x16x32_bf16(a, b, acc[nt], 0, 0, 0);
        }
    }

#pragma unroll
    for (int nt = 0; nt < 8; ++nt) {
        const int n = nt * 16 + m16;
#pragma unroll
        for (int r = 0; r < 4; ++r) {
            const int gp = blockIdx.x * 64 + w * 16 + q * 4 + r;
            if (n < 64) vout[(size_t)gp * CH + n] = acc[nt][r] + b1[n];
            else        ubuf[(size_t)gp * CH + (n - 64)] = f2bf(acc[nt][r]);
        }
    }
}

// ---------------------------------------------------------------------------
// edge: block = 8 points (128 edge rows). h = relu(v_i + u_j) staged bf16 in
// LDS; GEMM2 (128x64)@(64x64) via MFMA; max over each point's 16 rows; +b2.
// v_i lives in out[] (written by prep; only this block reads its own rows,
// and overwrites them only after consuming them -> no cross-block hazard).
// ---------------------------------------------------------------------------
__global__ __launch_bounds__(256) void edge_kernel(const unsigned short* __restrict__ ubuf,
                                                   const float* __restrict__ W2,
                                                   const float* __restrict__ b2,
                                                   const unsigned short* __restrict__ knn,
                                                   float* __restrict__ out) {
    __shared__ unsigned short h[128 * 72];    // edge-row tile bf16
    __shared__ unsigned short W2t[64 * 72];   // [e][d] bf16

    const int t    = threadIdx.x;
    const int lane = t & 63;
    const int w    = t >> 6;

    {   // W2^T -> bf16 LDS
        const int n = t & 63;
        const int kb = (t >> 6) * 16;
#pragma unroll
        for (int i = 0; i < 16; ++i) {
            const int k = kb + i;
            W2t[n * 72 + k] = f2bf(W2[k * 64 + n]);
        }
    }
    {   // h rows: iteration i handles point i of this block
        const int k = t >> 4;       // neighbor slot 0..15
        const int c = t & 15;       // 4-element chunk 0..15
#pragma unroll
        for (int i = 0; i < 8; ++i) {
            const int gn = blockIdx.x * 8 + i;
            const int gj = (int)knn[gn * 16 + k];
            const float4  vv = ((const float4*)(out + (size_t)gn * CH))[c];
            const ushort4 uu = ((const ushort4*)(ubuf + (size_t)gj * CH))[c];
            ushort4 hv;
            hv.x = f2bf(fmaxf(vv.x + bf2f(uu.x), 0.f));
            hv.y = f2bf(fmaxf(vv.y + bf2f(uu.y), 0.f));
            hv.z = f2bf(fmaxf(vv.z + bf2f(uu.z), 0.f));
            hv.w = f2bf(fmaxf(vv.w + bf2f(uu.w), 0.f));
            const int row = i * 16 + k;
            *(ushort4*)(h + row * 72 + c * 4) = hv;
        }
    }
    __syncthreads();

    const int m16 = lane & 15;
    const int q   = lane >> 4;

    floatx4 acc[2][4];
#pragma unroll
    for (int i = 0; i < 2; ++i)
#pragma unroll
        for (int nt = 0; nt < 4; ++nt) acc[i][nt] = (floatx4){0.f, 0.f, 0.f, 0.f};

#pragma unroll
    for (int kk = 0; kk < 64; kk += 32) {
        const short8 a0 = *(const short8*)(h + ((w * 2 + 0) * 16 + m16) * 72 + kk + q * 8);
        const short8 a1 = *(const short8*)(h + ((w * 2 + 1) * 16 + m16) * 72 + kk + q * 8);
#pragma unroll
        for (int nt = 0; nt < 4; ++nt) {
            const short8 b = *(const short8*)(W2t + (nt * 16 + m16) * 72 + kk + q * 8);
            acc[0][nt] = __builtin_amdgcn_mfma_f32_16x16x32_bf16(a0, b, acc[0][nt], 0, 0, 0);
            acc[1][nt] = __builtin_amdgcn_mfma_f32_16x16x32_bf16(a1, b, acc[1][nt], 0, 0, 0);
        }
    }

    // max over the 16 rows of each point's m-tile, +b2, store fp32
#pragma unroll
    for (int i = 0; i < 2; ++i) {
        const int mt = w * 2 + i;
        const int gn = blockIdx.x * 8 + mt;
#pragma unroll
        for (int nt = 0; nt < 4; ++nt) {
            float m0 = fmaxf(fmaxf(acc[i][nt][0], acc[i][nt][1]),
                             fmaxf(acc[i][nt][2], acc[i][nt][3]));
            m0 = fmaxf(m0, __shfl_xor(m0, 16));
            m0 = fmaxf(m0, __shfl_xor(m0, 32));
            if (lane < 16)
                out[(size_t)gn * CH + nt * 16 + lane] = m0 + b2[nt * 16 + lane];
        }
    }
}

extern "C" void kernel_launch(void* const* d_in, const int* in_sizes, int n_in,
                              void* d_out, int out_size, void* d_ws, size_t ws_size,
                              hipStream_t stream) {
    const float* x   = (const float*)d_in[0];
    const float* pos = (const float*)d_in[1];
    const float* W1  = (const float*)d_in[2];
    const float* b1  = (const float*)d_in[3];
    const float* W2  = (const float*)d_in[4];
    const float* b2  = (const float*)d_in[5];
    float* out = (float*)d_out;

    unsigned short* knn  = (unsigned short*)d_ws;               // 512 KB
    unsigned short* ubuf = (unsigned short*)((char*)d_ws + (size_t)NPTS * 16 * 2);  // 2 MB

    knn_kernel<<<NPTS / 16, 256, 0, stream>>>(pos, knn);
    prep_kernel<<<NPTS / 64, 256, 0, stream>>>(x, W1, b1, out, ubuf);
    edge_kernel<<<NPTS / 8, 256, 0, stream>>>(ubuf, W2, b2, knn, out);
}

// Round 6
// 235.905 us; speedup vs baseline: 1.3378x; 1.0528x over previous
//
#include <hip/hip_runtime.h>
#include <hip/hip_bf16.h>

// EdgeConv: N=16384 points, C=64, D=64, K=16 neighbors. All I/O fp32.
// Pipeline:
//   1) knn_kernel : exact 16-NN per point (fp32 distances, LDS-staged pos)
//   2) prep_kernel: v = x@(W1a-W1b)+b1 -> d_out (fp32, block-local reuse only)
//                   u = x@W1b          -> ws   (bf16, gathered by neighbor)
//   3) edge_kernel: h = relu(v_i + u_j); out = max_k(h @ W2) + b2
// ws usage: knn ushort 512KB @0, u bf16 2MB @512KB (total 2.5MB).
// R6: occupancy experiment -- 2 rows/wave (was 4), grid 2048 (was 1024),
// CHUNK 1024 (16KB LDS) -> 8 blocks/CU, 32 waves/CU (100%) vs previous 36%.
// Tests the latency-bound hypothesis (static VALU count predicts ~27us but
// kernel runs 180us; ds_read+FMA-chain latency at 4 waves/SIMD is the gap).

#define NPTS 16384
#define CH 64

typedef __attribute__((ext_vector_type(8))) short short8;
typedef __attribute__((ext_vector_type(4))) float floatx4;

__device__ __forceinline__ unsigned short f2bf(float f) {
    unsigned u = __float_as_uint(f);
    u += 0x7FFFu + ((u >> 16) & 1u);   // RNE
    return (unsigned short)(u >> 16);
}
__device__ __forceinline__ float bf2f(unsigned short u) {
    return __uint_as_float(((unsigned)u) << 16);
}

// 64-bit DPP row_shr:1 (shift within 16-lane DPP rows; lanes 0/16/32/48 get 0).
// Our sorted list lives in lanes 0..15, so this is exactly shfl_up-by-1 there.
__device__ __forceinline__ unsigned long long dpp_shr1_u64(unsigned long long x) {
    int lo = (int)(unsigned)(x & 0xFFFFFFFFULL);
    int hi = (int)(unsigned)(x >> 32);
    lo = __builtin_amdgcn_update_dpp(0, lo, 0x111, 0xF, 0xF, false);
    hi = __builtin_amdgcn_update_dpp(0, hi, 0x111, 0xF, 0xF, false);
    return (((unsigned long long)(unsigned)hi) << 32) | (unsigned)lo;
}

// ---------------------------------------------------------------------------
// KNN. Block = 256 thr = 4 waves, each wave owns 2 rows. pos staged in LDS
// as float4{x,y,z,sq} chunks of 1024 (16 KB). Top-16 = distributed sorted
// u64 keys (monotone float bits << 32 | idx) in lanes 0..15.
// Warm start: bitonic-sort the first 64 candidates' keys -> exact initial
// top-16 + finite tau, eliminating the tau=+inf insert flood.
// ---------------------------------------------------------------------------
#define CHUNK 1024
#define ROWS_PER_WAVE 2
#define SENT 0xFF800000FFFFFFFFULL   // key(+inf) | idx-all-ones

__global__ __launch_bounds__(256) void knn_kernel(const float* __restrict__ pos,
                                                  unsigned short* __restrict__ knn_out) {
    __shared__ float4 sp[CHUNK];
    const int t    = threadIdx.x;
    const int lane = t & 63;
    const int w    = t >> 6;
    const int row0 = blockIdx.x * (4 * ROWS_PER_WAVE) + w * ROWS_PER_WAVE;

    float xi[ROWS_PER_WAVE], yi[ROWS_PER_WAVE], zi[ROWS_PER_WAVE], sqi[ROWS_PER_WAVE];
#pragma unroll
    for (int r = 0; r < ROWS_PER_WAVE; ++r) {
        xi[r]  = pos[(row0 + r) * 3 + 0];
        yi[r]  = pos[(row0 + r) * 3 + 1];
        zi[r]  = pos[(row0 + r) * 3 + 2];
        sqi[r] = xi[r] * xi[r] + yi[r] * yi[r] + zi[r] * zi[r];
    }

    unsigned long long list[ROWS_PER_WAVE];
    float tau[ROWS_PER_WAVE];

    for (int c0 = 0; c0 < NPTS; c0 += CHUNK) {
        __syncthreads();   // previous chunk's readers done
        for (int i = t; i < CHUNK; i += 256) {
            const int j = c0 + i;
            const float a = pos[j * 3 + 0];
            const float b = pos[j * 3 + 1];
            const float c = pos[j * 3 + 2];
            sp[i] = make_float4(a, b, c, a * a + b * b + c * c);
        }
        __syncthreads();

        int it0 = 0;
        if (c0 == 0) {
            // ---- warm start: exact top-16 of candidates 0..63 via bitonic sort
            const float4 p = sp[lane];
#pragma unroll
            for (int r = 0; r < ROWS_PER_WAVE; ++r) {
                const float dot = fmaf(xi[r], p.x, fmaf(yi[r], p.y, zi[r] * p.z));
                const float d   = fmaf(-2.0f, dot, sqi[r] + p.w);
                unsigned kd = __float_as_uint(d);
                kd = ((int)kd < 0) ? ~kd : (kd | 0x80000000u);
                unsigned long long key =
                    (((unsigned long long)kd) << 32) | (unsigned)lane;
                if (lane == row0 + r) key = SENT;   // self-exclusion
                // 64-lane bitonic sort, ascending by lane
#pragma unroll
                for (int k = 2; k <= 64; k <<= 1) {
#pragma unroll
                    for (int j = k >> 1; j >= 1; j >>= 1) {
                        const unsigned long long o = __shfl_xor(key, j);
                        const bool takeMin =
                            (((lane & k) == 0) == ((lane & j) == 0));
                        const unsigned long long mn = (key < o) ? key : o;
                        const unsigned long long mx = (key < o) ? o : key;
                        key = takeMin ? mn : mx;
                    }
                }
                list[r] = key;   // lanes 0..15 = smallest 16, sorted
                const unsigned thi = (unsigned)__builtin_amdgcn_readlane(
                    (int)(unsigned)(key >> 32), 15);
                const unsigned fb =
                    (thi >= 0x80000000u) ? (thi & 0x7FFFFFFFu) : ~thi;
                tau[r] = __uint_as_float(fb);
            }
            it0 = 64;
        }

        for (int it = it0; it < CHUNK; it += 64) {
            const float4 p = sp[it + lane];
            const int base = c0 + it;
#pragma unroll
            for (int r = 0; r < ROWS_PER_WAVE; ++r) {
                const float dot = fmaf(xi[r], p.x, fmaf(yi[r], p.y, zi[r] * p.z));
                const float d   = fmaf(-2.0f, dot, sqi[r] + p.w);
                unsigned long long mask = __ballot(d <= tau[r]);
                if (mask) {
                    const int row = row0 + r;
                    if ((unsigned)(row - base) < 64u)
                        mask &= ~(1ULL << (row - base));   // drop self
                    if (mask) {
                        // event path: build key only now
                        unsigned kd = __float_as_uint(d);
                        kd = ((int)kd < 0) ? ~kd : (kd | 0x80000000u);
                        const unsigned klo = (unsigned)(base + lane);
                        do {
                            const int src = __ffsll(mask) - 1;
                            mask &= mask - 1;
                            const unsigned slo = (unsigned)__builtin_amdgcn_readlane((int)klo, src);
                            const unsigned shi = (unsigned)__builtin_amdgcn_readlane((int)kd, src);
                            const unsigned long long v =
                                (((unsigned long long)shi) << 32) | slo;
                            const unsigned long long prev = dpp_shr1_u64(list[r]);
                            const unsigned long long lr = list[r];
                            list[r] = (lr < v) ? lr : ((prev < v) ? v : prev);
                        } while (mask);
                        // tau = float of list[15]'s distance bits
                        const unsigned thi = (unsigned)__builtin_amdgcn_readlane(
                            (int)(unsigned)(list[r] >> 32), 15);
                        const unsigned fb =
                            (thi >= 0x80000000u) ? (thi & 0x7FFFFFFFu) : ~thi;
                        tau[r] = __uint_as_float(fb);
                    }
                }
            }
        }
    }
#pragma unroll
    for (int r = 0; r < ROWS_PER_WAVE; ++r)
        if (lane < 16)
            knn_out[(row0 + r) * 16 + lane] =
                (unsigned short)(unsigned)(list[r] & 0xFFFFULL);
}

// ---------------------------------------------------------------------------
// prep: v_p = x_p@(W1a - W1b) + b1 -> vout (fp32, == d_out)
//       u_p = x_p@W1b              -> ubuf (bf16)
// Block = 64 points. bf16 MFMA 16x16x32, fp32 accumulate.
// ---------------------------------------------------------------------------
__global__ __launch_bounds__(256) void prep_kernel(const float* __restrict__ x,
                                                   const float* __restrict__ W1,
                                                   const float* __restrict__ b1,
                                                   float* __restrict__ vout,
                                                   unsigned short* __restrict__ ubuf) {
    __shared__ unsigned short Wct[128 * 72];  // [n][k] bf16, n<64: (W1a-W1b) col, else W1b
    __shared__ unsigned short Abuf[64 * 72];  // x tile bf16 [row][k]
    __shared__ float Wraw[128 * 64];          // raw W1 fp32

    const int t    = threadIdx.x;
    const int lane = t & 63;
    const int w    = t >> 6;

    {   // coalesced W1 load
        const float4* W1v = (const float4*)W1;   // 2048 float4
        float4* Wr4 = (float4*)Wraw;
#pragma unroll
        for (int i = 0; i < 8; ++i) Wr4[i * 256 + t] = W1v[i * 256 + t];
    }
    __syncthreads();
    {   // build Wct[n][k]
        const int n = t & 127;
        const int ks = (t >> 7) * 32;
#pragma unroll
        for (int i = 0; i < 32; ++i) {
            const int k = ks + i;
            float val;
            if (n < 64) val = Wraw[k * 64 + n] - Wraw[(64 + k) * 64 + n];
            else        val = Wraw[(64 + k) * 64 + (n - 64)];
            Wct[n * 72 + k] = f2bf(val);
        }
    }
    {   // stage x tile -> bf16
        const int col = t & 63;
#pragma unroll
        for (int i = 0; i < 16; ++i) {
            const int row = (t >> 6) + 4 * i;
            const int gp = blockIdx.x * 64 + row;
            Abuf[row * 72 + col] = f2bf(x[(size_t)gp * CH + col]);
        }
    }
    __syncthreads();

    const int m16 = lane & 15;
    const int q   = lane >> 4;

    floatx4 acc[8];
#pragma unroll
    for (int nt = 0; nt < 8; ++nt) acc[nt] = (floatx4){0.f, 0.f, 0.f, 0.f};

#pragma unroll
    for (int kk = 0; kk < 64; kk += 32) {
        const short8 a = *(const short8*)(Abuf + (w * 16 + m16) * 72 + kk + q * 8);
#pragma unroll
        for (int nt = 0; nt < 8; ++nt) {
            const short8 b = *(const short8*)(Wct + (nt * 16 + m16) * 72 + kk + q * 8);
            acc[nt] = __builtin_amdgcn_mfma_f32_16x16x32_bf16(a, b, acc[nt], 0, 0, 0);
        }
    }

#pragma unroll
    for (int nt = 0; nt < 8; ++nt) {
        const int n = nt * 16 + m16;
#pragma unroll
        for (int r = 0; r < 4; ++r) {
            const int gp = blockIdx.x * 64 + w * 16 + q * 4 + r;
            if (n < 64) vout[(size_t)gp * CH + n] = acc[nt][r] + b1[n];
            else        ubuf[(size_t)gp * CH + (n - 64)] = f2bf(acc[nt][r]);
        }
    }
}

// ---------------------------------------------------------------------------
// edge: block = 8 points (128 edge rows). h = relu(v_i + u_j) staged bf16 in
// LDS; GEMM2 (128x64)@(64x64) via MFMA; max over each point's 16 rows; +b2.
// v_i lives in out[] (written by prep; only this block reads its own rows,
// and overwrites them only after consuming them -> no cross-block hazard).
// ---------------------------------------------------------------------------
__global__ __launch_bounds__(256) void edge_kernel(const unsigned short* __restrict__ ubuf,
                                                   const float* __restrict__ W2,
                                                   const float* __restrict__ b2,
                                                   const unsigned short* __restrict__ knn,
                                                   float* __restrict__ out) {
    __shared__ unsigned short h[128 * 72];    // edge-row tile bf16
    __shared__ unsigned short W2t[64 * 72];   // [e][d] bf16

    const int t    = threadIdx.x;
    const int lane = t & 63;
    const int w    = t >> 6;

    {   // W2^T -> bf16 LDS
        const int n = t & 63;
        const int kb = (t >> 6) * 16;
#pragma unroll
        for (int i = 0; i < 16; ++i) {
            const int k = kb + i;
            W2t[n * 72 + k] = f2bf(W2[k * 64 + n]);
        }
    }
    {   // h rows: iteration i handles point i of this block
        const int k = t >> 4;       // neighbor slot 0..15
        const int c = t & 15;       // 4-element chunk 0..15
#pragma unroll
        for (int i = 0; i < 8; ++i) {
            const int gn = blockIdx.x * 8 + i;
            const int gj = (int)knn[gn * 16 + k];
            const float4  vv = ((const float4*)(out + (size_t)gn * CH))[c];
            const ushort4 uu = ((const ushort4*)(ubuf + (size_t)gj * CH))[c];
            ushort4 hv;
            hv.x = f2bf(fmaxf(vv.x + bf2f(uu.x), 0.f));
            hv.y = f2bf(fmaxf(vv.y + bf2f(uu.y), 0.f));
            hv.z = f2bf(fmaxf(vv.z + bf2f(uu.z), 0.f));
            hv.w = f2bf(fmaxf(vv.w + bf2f(uu.w), 0.f));
            const int row = i * 16 + k;
            *(ushort4*)(h + row * 72 + c * 4) = hv;
        }
    }
    __syncthreads();

    const int m16 = lane & 15;
    const int q   = lane >> 4;

    floatx4 acc[2][4];
#pragma unroll
    for (int i = 0; i < 2; ++i)
#pragma unroll
        for (int nt = 0; nt < 4; ++nt) acc[i][nt] = (floatx4){0.f, 0.f, 0.f, 0.f};

#pragma unroll
    for (int kk = 0; kk < 64; kk += 32) {
        const short8 a0 = *(const short8*)(h + ((w * 2 + 0) * 16 + m16) * 72 + kk + q * 8);
        const short8 a1 = *(const short8*)(h + ((w * 2 + 1) * 16 + m16) * 72 + kk + q * 8);
#pragma unroll
        for (int nt = 0; nt < 4; ++nt) {
            const short8 b = *(const short8*)(W2t + (nt * 16 + m16) * 72 + kk + q * 8);
            acc[0][nt] = __builtin_amdgcn_mfma_f32_16x16x32_bf16(a0, b, acc[0][nt], 0, 0, 0);
            acc[1][nt] = __builtin_amdgcn_mfma_f32_16x16x32_bf16(a1, b, acc[1][nt], 0, 0, 0);
        }
    }

    // max over the 16 rows of each point's m-tile, +b2, store fp32
#pragma unroll
    for (int i = 0; i < 2; ++i) {
        const int mt = w * 2 + i;
        const int gn = blockIdx.x * 8 + mt;
#pragma unroll
        for (int nt = 0; nt < 4; ++nt) {
            float m0 = fmaxf(fmaxf(acc[i][nt][0], acc[i][nt][1]),
                             fmaxf(acc[i][nt][2], acc[i][nt][3]));
            m0 = fmaxf(m0, __shfl_xor(m0, 16));
            m0 = fmaxf(m0, __shfl_xor(m0, 32));
            if (lane < 16)
                out[(size_t)gn * CH + nt * 16 + lane] = m0 + b2[nt * 16 + lane];
        }
    }
}

extern "C" void kernel_launch(void* const* d_in, const int* in_sizes, int n_in,
                              void* d_out, int out_size, void* d_ws, size_t ws_size,
                              hipStream_t stream) {
    const float* x   = (const float*)d_in[0];
    const float* pos = (const float*)d_in[1];
    const float* W1  = (const float*)d_in[2];
    const float* b1  = (const float*)d_in[3];
    const float* W2  = (const float*)d_in[4];
    const float* b2  = (const float*)d_in[5];
    float* out = (float*)d_out;

    unsigned short* knn  = (unsigned short*)d_ws;               // 512 KB
    unsigned short* ubuf = (unsigned short*)((char*)d_ws + (size_t)NPTS * 16 * 2);  // 2 MB

    knn_kernel<<<NPTS / 8, 256, 0, stream>>>(pos, knn);
    prep_kernel<<<NPTS / 64, 256, 0, stream>>>(x, W1, b1, out, ubuf);
    edge_kernel<<<NPTS / 8, 256, 0, stream>>>(ubuf, W2, b2, knn, out);
}

// Round 8
// 218.069 us; speedup vs baseline: 1.4472x; 1.0818x over previous
//
#include <hip/hip_runtime.h>
#include <hip/hip_bf16.h>

// EdgeConv: N=16384 points, C=64, D=64, K=16 neighbors. All I/O fp32.
// Pipeline:
//   grid build (zero/count/scan/scatter) -> exact grid KNN (shell expansion)
//   prep_kernel: v = x@(W1a-W1b)+b1 -> d_out ; u = x@W1b -> ws (bf16)
//   edge_kernel: h = relu(v_i + u_j); out = max_k(h @ W2) + b2
// R8: R7's absmax 1.09 was the distance-formula switch (diff^2 is uncorrelated
// with the reference's cancellation error -> near-tie neighbor flips). Restore
// the EXACT R6 arithmetic: d = fmaf(-2, dot, sq_i + sq_j), sq staged at
// scatter; termination margin tau + 1e-4 covers formula-vs-geometry skew.
// ws: knn 512K, ubuf 2M, counts/starts/cursor 128K ea, spos 256K, sidx 32K.

#define NPTS 16384
#define CH 64

#define GLO  (-4.5f)
#define GH   0.28125f          // 9/32
#define INVH 3.5555555556f     // 32/9
#define GDIM 32
#define GCELLS (GDIM * GDIM * GDIM)

typedef __attribute__((ext_vector_type(8))) short short8;
typedef __attribute__((ext_vector_type(4))) float floatx4;

__device__ __forceinline__ unsigned short f2bf(float f) {
    unsigned u = __float_as_uint(f);
    u += 0x7FFFu + ((u >> 16) & 1u);   // RNE
    return (unsigned short)(u >> 16);
}
__device__ __forceinline__ float bf2f(unsigned short u) {
    return __uint_as_float(((unsigned)u) << 16);
}

// 64-bit DPP row_shr:1 (shift within 16-lane DPP rows; lane 0 gets 0).
// Sorted list lives in lanes 0..15, so this is shfl_up-by-1 there.
__device__ __forceinline__ unsigned long long dpp_shr1_u64(unsigned long long x) {
    int lo = (int)(unsigned)(x & 0xFFFFFFFFULL);
    int hi = (int)(unsigned)(x >> 32);
    lo = __builtin_amdgcn_update_dpp(0, lo, 0x111, 0xF, 0xF, false);
    hi = __builtin_amdgcn_update_dpp(0, hi, 0x111, 0xF, 0xF, false);
    return (((unsigned long long)(unsigned)hi) << 32) | (unsigned)lo;
}

__device__ __forceinline__ int cell_of(float x, float y, float z) {
    int cx = (int)floorf((x - GLO) * INVH);
    int cy = (int)floorf((y - GLO) * INVH);
    int cz = (int)floorf((z - GLO) * INVH);
    cx = min(max(cx, 0), GDIM - 1);
    cy = min(max(cy, 0), GDIM - 1);
    cz = min(max(cz, 0), GDIM - 1);
    return (cz * GDIM + cy) * GDIM + cx;
}

// ---------------------------------------------------------------------------
// Grid build
// ---------------------------------------------------------------------------
__global__ __launch_bounds__(256) void zero_kernel(int* __restrict__ counts) {
    counts[blockIdx.x * 256 + threadIdx.x] = 0;
}

__global__ __launch_bounds__(256) void grid_count_kernel(const float* __restrict__ pos,
                                                         int* __restrict__ counts) {
    const int i = blockIdx.x * 256 + threadIdx.x;
    atomicAdd(&counts[cell_of(pos[i * 3], pos[i * 3 + 1], pos[i * 3 + 2])], 1);
}

__global__ __launch_bounds__(1024) void scan_kernel(const int* __restrict__ counts,
                                                    int* __restrict__ starts,
                                                    int* __restrict__ cursor) {
    __shared__ int lds[1024];
    const int t = threadIdx.x;
    int sum = 0;
#pragma unroll
    for (int i = 0; i < 32; ++i) sum += counts[t * 32 + i];
    lds[t] = sum;
    __syncthreads();
    for (int off = 1; off < 1024; off <<= 1) {
        int v = 0;
        if (t >= off) v = lds[t - off];
        __syncthreads();
        lds[t] += v;
        __syncthreads();
    }
    int pre = (t == 0) ? 0 : lds[t - 1];
#pragma unroll
    for (int i = 0; i < 32; ++i) {
        starts[t * 32 + i] = pre;
        cursor[t * 32 + i] = pre;
        pre += counts[t * 32 + i];
    }
}

__global__ __launch_bounds__(256) void grid_scatter_kernel(const float* __restrict__ pos,
                                                           int* __restrict__ cursor,
                                                           float4* __restrict__ spos,
                                                           unsigned short* __restrict__ sidx) {
    const int i = blockIdx.x * 256 + threadIdx.x;
    const float a = pos[i * 3], b = pos[i * 3 + 1], c = pos[i * 3 + 2];
    const int dst = atomicAdd(&cursor[cell_of(a, b, c)], 1);
    // sq computed with the SAME expression as the query side / R6 staging
    spos[dst] = make_float4(a, b, c, a * a + b * b + c * c);
    sidx[dst] = (unsigned short)i;
}

// ---------------------------------------------------------------------------
// Grid KNN search: 1 wave per query. Shell expansion around the query's cell;
// top-16 = distributed sorted u64 keys (monotone dist bits << 32 | orig idx)
// in lanes 0..15; exact termination via processed-cube boundary distance.
// Distance uses the reference formula d = (sq_i + sq_j) - 2*dot, identical
// fmaf structure to the R6 brute-force kernel (correlated rounding with ref).
// ---------------------------------------------------------------------------
#define SENT 0xFF800000FFFFFFFFULL   // key(+inf) | idx-all-ones

__global__ __launch_bounds__(256) void knn_grid_kernel(const float* __restrict__ pos,
                                                       const float4* __restrict__ spos,
                                                       const unsigned short* __restrict__ sidx,
                                                       const int* __restrict__ starts,
                                                       const int* __restrict__ counts,
                                                       unsigned short* __restrict__ knn_out) {
    const int lane = threadIdx.x & 63;
    const int row  = blockIdx.x * 4 + (threadIdx.x >> 6);

    const float qx = pos[row * 3 + 0];
    const float qy = pos[row * 3 + 1];
    const float qz = pos[row * 3 + 2];
    const float sqi = qx * qx + qy * qy + qz * qz;
    int cix = min(max((int)floorf((qx - GLO) * INVH), 0), GDIM - 1);
    int ciy = min(max((int)floorf((qy - GLO) * INVH), 0), GDIM - 1);
    int ciz = min(max((int)floorf((qz - GLO) * INVH), 0), GDIM - 1);

    unsigned long long list = SENT;
    float tau = __uint_as_float(0x7F800000u);   // +INF

    int pax = 1, pbx = 0, pay = 1, pby = 0, paz = 1, pbz = 0;  // empty prev cube

    for (int s = 0; s < GDIM; ++s) {
        const int ax = max(cix - s, 0), bx = min(cix + s, GDIM - 1);
        const int ay = max(ciy - s, 0), by = min(ciy + s, GDIM - 1);
        const int az = max(ciz - s, 0), bz = min(ciz + s, GDIM - 1);
        const int dx = bx - ax + 1, dy = by - ay + 1, dz = bz - az + 1;
        const int A = dx * dy, vol = A * dz;
        const float invA = 1.0f / (float)A, invB = 1.0f / (float)dx;

        for (int base = 0; base < vol; base += 64) {
            const int li = base + lane;
            int cnt = 0, st = 0;
            if (li < vol) {
                const int oz  = (int)(((float)li + 0.5f) * invA);
                const int rem = li - oz * A;
                const int oy  = (int)(((float)rem + 0.5f) * invB);
                const int ox  = rem - oy * dx;
                const int cx = ax + ox, cy = ay + oy, cz = az + oz;
                const bool inner = (s > 0) && cx >= pax && cx <= pbx &&
                                   cy >= pay && cy <= pby && cz >= paz && cz <= pbz;
                if (!inner) {
                    const int cell = (cz * GDIM + cy) * GDIM + cx;
                    cnt = counts[cell];
                    st  = starts[cell];
                }
            }
            unsigned long long cm = __ballot(cnt > 0);
            while (cm) {
                const int e = __ffsll(cm) - 1;
                cm &= cm - 1;
                const int scnt = __builtin_amdgcn_readlane(cnt, e);
                const int sst  = __builtin_amdgcn_readlane(st, e);
                for (int cb = 0; cb < scnt; cb += 64) {
                    const int c2  = cb + lane;
                    const int idx = sst + min(c2, scnt - 1);
                    const float4 p = spos[idx];
                    const int jorig = (int)sidx[idx];
                    // reference-formula distance (matches R6 exactly)
                    const float dot = fmaf(qx, p.x, fmaf(qy, p.y, qz * p.z));
                    const float d   = fmaf(-2.0f, dot, sqi + p.w);
                    const bool cand = (c2 < scnt) && (jorig != row) && (d <= tau);
                    unsigned long long mask = __ballot(cand);
                    if (mask) {
                        unsigned kd = __float_as_uint(d);
                        kd = ((int)kd < 0) ? ~kd : (kd | 0x80000000u);  // monotone
                        do {
                            const int src = __ffsll(mask) - 1;
                            mask &= mask - 1;
                            const unsigned slo = (unsigned)__builtin_amdgcn_readlane(jorig, src);
                            const unsigned shi = (unsigned)__builtin_amdgcn_readlane((int)kd, src);
                            const unsigned long long v =
                                (((unsigned long long)shi) << 32) | slo;
                            const unsigned long long prev = dpp_shr1_u64(list);
                            const unsigned long long lr = list;
                            list = (lr < v) ? lr : ((prev < v) ? v : prev);
                        } while (mask);
                        const unsigned thi = (unsigned)__builtin_amdgcn_readlane(
                            (int)(unsigned)(list >> 32), 15);
                        const unsigned fb =
                            (thi >= 0x80000000u) ? (thi & 0x7FFFFFFFu) : ~thi;
                        tau = __uint_as_float(fb);
                    }
                }
            }
        }

        // termination: min geometric distance from q to unprocessed region.
        // tau lives in ref-formula space (can undershoot geometry by ~5e-6),
        // so keep a 1e-4 safety margin before declaring the search done.
        const float BIG = 1e30f;
        float dout = BIG;
        if (ax > 0)        dout = fminf(dout, qx - (GLO + ax * GH));
        if (bx < GDIM - 1) dout = fminf(dout, (GLO + (bx + 1) * GH) - qx);
        if (ay > 0)        dout = fminf(dout, qy - (GLO + ay * GH));
        if (by < GDIM - 1) dout = fminf(dout, (GLO + (by + 1) * GH) - qy);
        if (az > 0)        dout = fminf(dout, qz - (GLO + az * GH));
        if (bz < GDIM - 1) dout = fminf(dout, (GLO + (bz + 1) * GH) - qz);
        if (dout * dout > tau + 1e-4f) break;
        if (ax == 0 && bx == GDIM - 1 && ay == 0 && by == GDIM - 1 &&
            az == 0 && bz == GDIM - 1) break;
        pax = ax; pbx = bx; pay = ay; pby = by; paz = az; pbz = bz;
    }

    if (lane < 16)
        knn_out[row * 16 + lane] = (unsigned short)(list & 0xFFFFULL);
}

// ---------------------------------------------------------------------------
// prep: v_p = x_p@(W1a - W1b) + b1 -> vout (fp32, == d_out)
//       u_p = x_p@W1b              -> ubuf (bf16)
// Block = 64 points. bf16 MFMA 16x16x32, fp32 accumulate.
// ---------------------------------------------------------------------------
__global__ __launch_bounds__(256) void prep_kernel(const float* __restrict__ x,
                                                   const float* __restrict__ W1,
                                                   const float* __restrict__ b1,
                                                   float* __restrict__ vout,
                                                   unsigned short* __restrict__ ubuf) {
    __shared__ unsigned short Wct[128 * 72];  // [n][k] bf16, n<64: (W1a-W1b) col, else W1b
    __shared__ unsigned short Abuf[64 * 72];  // x tile bf16 [row][k]
    __shared__ float Wraw[128 * 64];          // raw W1 fp32

    const int t    = threadIdx.x;
    const int lane = t & 63;
    const int w    = t >> 6;

    {   // coalesced W1 load
        const float4* W1v = (const float4*)W1;   // 2048 float4
        float4* Wr4 = (float4*)Wraw;
#pragma unroll
        for (int i = 0; i < 8; ++i) Wr4[i * 256 + t] = W1v[i * 256 + t];
    }
    __syncthreads();
    {   // build Wct[n][k]
        const int n = t & 127;
        const int ks = (t >> 7) * 32;
#pragma unroll
        for (int i = 0; i < 32; ++i) {
            const int k = ks + i;
            float val;
            if (n < 64) val = Wraw[k * 64 + n] - Wraw[(64 + k) * 64 + n];
            else        val = Wraw[(64 + k) * 64 + (n - 64)];
            Wct[n * 72 + k] = f2bf(val);
        }
    }
    {   // stage x tile -> bf16
        const int col = t & 63;
#pragma unroll
        for (int i = 0; i < 16; ++i) {
            const int row = (t >> 6) + 4 * i;
            const int gp = blockIdx.x * 64 + row;
            Abuf[row * 72 + col] = f2bf(x[(size_t)gp * CH + col]);
        }
    }
    __syncthreads();

    const int m16 = lane & 15;
    const int q   = lane >> 4;

    floatx4 acc[8];
#pragma unroll
    for (int nt = 0; nt < 8; ++nt) acc[nt] = (floatx4){0.f, 0.f, 0.f, 0.f};

#pragma unroll
    for (int kk = 0; kk < 64; kk += 32) {
        const short8 a = *(const short8*)(Abuf + (w * 16 + m16) * 72 + kk + q * 8);
#pragma unroll
        for (int nt = 0; nt < 8; ++nt) {
            const short8 b = *(const short8*)(Wct + (nt * 16 + m16) * 72 + kk + q * 8);
            acc[nt] = __builtin_amdgcn_mfma_f32_16x16x32_bf16(a, b, acc[nt], 0, 0, 0);
        }
    }

#pragma unroll
    for (int nt = 0; nt < 8; ++nt) {
        const int n = nt * 16 + m16;
#pragma unroll
        for (int r = 0; r < 4; ++r) {
            const int gp = blockIdx.x * 64 + w * 16 + q * 4 + r;
            if (n < 64) vout[(size_t)gp * CH + n] = acc[nt][r] + b1[n];
            else        ubuf[(size_t)gp * CH + (n - 64)] = f2bf(acc[nt][r]);
        }
    }
}

// ---------------------------------------------------------------------------
// edge: block = 8 points (128 edge rows). h = relu(v_i + u_j) staged bf16 in
// LDS; GEMM2 (128x64)@(64x64) via MFMA; max over each point's 16 rows; +b2.
// v_i lives in out[] (written by prep; only this block reads its own rows,
// and overwrites them only after consuming them -> no cross-block hazard).
// ---------------------------------------------------------------------------
__global__ __launch_bounds__(256) void edge_kernel(const unsigned short* __restrict__ ubuf,
                                                   const float* __restrict__ W2,
                                                   const float* __restrict__ b2,
                                                   const unsigned short* __restrict__ knn,
                                                   float* __restrict__ out) {
    __shared__ unsigned short h[128 * 72];    // edge-row tile bf16
    __shared__ unsigned short W2t[64 * 72];   // [e][d] bf16

    const int t    = threadIdx.x;
    const int lane = t & 63;
    const int w    = t >> 6;

    {   // W2^T -> bf16 LDS
        const int n = t & 63;
        const int kb = (t >> 6) * 16;
#pragma unroll
        for (int i = 0; i < 16; ++i) {
            const int k = kb + i;
            W2t[n * 72 + k] = f2bf(W2[k * 64 + n]);
        }
    }
    {   // h rows: iteration i handles point i of this block
        const int k = t >> 4;       // neighbor slot 0..15
        const int c = t & 15;       // 4-element chunk 0..15
#pragma unroll
        for (int i = 0; i < 8; ++i) {
            const int gn = blockIdx.x * 8 + i;
            const int gj = (int)knn[gn * 16 + k];
            const float4  vv = ((const float4*)(out + (size_t)gn * CH))[c];
            const ushort4 uu = ((const ushort4*)(ubuf + (size_t)gj * CH))[c];
            ushort4 hv;
            hv.x = f2bf(fmaxf(vv.x + bf2f(uu.x), 0.f));
            hv.y = f2bf(fmaxf(vv.y + bf2f(uu.y), 0.f));
            hv.z = f2bf(fmaxf(vv.z + bf2f(uu.z), 0.f));
            hv.w = f2bf(fmaxf(vv.w + bf2f(uu.w), 0.f));
            const int row = i * 16 + k;
            *(ushort4*)(h + row * 72 + c * 4) = hv;
        }
    }
    __syncthreads();

    const int m16 = lane & 15;
    const int q   = lane >> 4;

    floatx4 acc[2][4];
#pragma unroll
    for (int i = 0; i < 2; ++i)
#pragma unroll
        for (int nt = 0; nt < 4; ++nt) acc[i][nt] = (floatx4){0.f, 0.f, 0.f, 0.f};

#pragma unroll
    for (int kk = 0; kk < 64; kk += 32) {
        const short8 a0 = *(const short8*)(h + ((w * 2 + 0) * 16 + m16) * 72 + kk + q * 8);
        const short8 a1 = *(const short8*)(h + ((w * 2 + 1) * 16 + m16) * 72 + kk + q * 8);
#pragma unroll
        for (int nt = 0; nt < 4; ++nt) {
            const short8 b = *(const short8*)(W2t + (nt * 16 + m16) * 72 + kk + q * 8);
            acc[0][nt] = __builtin_amdgcn_mfma_f32_16x16x32_bf16(a0, b, acc[0][nt], 0, 0, 0);
            acc[1][nt] = __builtin_amdgcn_mfma_f32_16x16x32_bf16(a1, b, acc[1][nt], 0, 0, 0);
        }
    }

    // max over the 16 rows of each point's m-tile, +b2, store fp32
#pragma unroll
    for (int i = 0; i < 2; ++i) {
        const int mt = w * 2 + i;
        const int gn = blockIdx.x * 8 + mt;
#pragma unroll
        for (int nt = 0; nt < 4; ++nt) {
            float m0 = fmaxf(fmaxf(acc[i][nt][0], acc[i][nt][1]),
                             fmaxf(acc[i][nt][2], acc[i][nt][3]));
            m0 = fmaxf(m0, __shfl_xor(m0, 16));
            m0 = fmaxf(m0, __shfl_xor(m0, 32));
            if (lane < 16)
                out[(size_t)gn * CH + nt * 16 + lane] = m0 + b2[nt * 16 + lane];
        }
    }
}

extern "C" void kernel_launch(void* const* d_in, const int* in_sizes, int n_in,
                              void* d_out, int out_size, void* d_ws, size_t ws_size,
                              hipStream_t stream) {
    const float* x   = (const float*)d_in[0];
    const float* pos = (const float*)d_in[1];
    const float* W1  = (const float*)d_in[2];
    const float* b1  = (const float*)d_in[3];
    const float* W2  = (const float*)d_in[4];
    const float* b2  = (const float*)d_in[5];
    float* out = (float*)d_out;

    char* ws = (char*)d_ws;
    unsigned short* knn  = (unsigned short*)ws;                    // 512 KB @ 0
    unsigned short* ubuf = (unsigned short*)(ws + 524288);         // 2 MB
    int*    counts = (int*)(ws + 2621440);                         // 128 KB
    int*    starts = (int*)(ws + 2752512);                         // 128 KB
    int*    cursor = (int*)(ws + 2883584);                         // 128 KB
    float4* spos   = (float4*)(ws + 3014656);                      // 256 KB
    unsigned short* sidx = (unsigned short*)(ws + 3276800);        // 32 KB

    zero_kernel<<<GCELLS / 256, 256, 0, stream>>>(counts);
    grid_count_kernel<<<NPTS / 256, 256, 0, stream>>>(pos, counts);
    scan_kernel<<<1, 1024, 0, stream>>>(counts, starts, cursor);
    grid_scatter_kernel<<<NPTS / 256, 256, 0, stream>>>(pos, cursor, spos, sidx);
    knn_grid_kernel<<<NPTS / 4, 256, 0, stream>>>(pos, spos, sidx, starts, counts, knn);
    prep_kernel<<<NPTS / 64, 256, 0, stream>>>(x, W1, b1, out, ubuf);
    edge_kernel<<<NPTS / 8, 256, 0, stream>>>(ubuf, W2, b2, knn, out);
}

// Round 9
// 151.785 us; speedup vs baseline: 2.0792x; 1.4367x over previous
//
#include <hip/hip_runtime.h>
#include <hip/hip_bf16.h>

// EdgeConv: N=16384 points, C=64, D=64, K=16 neighbors. All I/O fp32.
// Pipeline:
//   grid build (zero/count/scan/scatter) -> exact grid KNN (shell expansion)
//   prep_kernel: v = x@(W1a-W1b)+b1 -> d_out ; u = x@W1b -> ws (bf16)
//   edge_kernel: h = relu(v_i + u_j); out = max_k(h @ W2) + b2
// R9: knn was serial-latency + tail bound (VALU 44%, occ 31%). Replace the
// serial per-cell loop with lane-parallel RUN enumeration (x-rows of cells
// are contiguous in spos) + wave prefix-scan + LDS binary-search compaction:
// dense 64-wide candidate batches, ~100% lane utilization, shell overhead
// ~10x down. Numerics identical to R8 (ref-formula distance, monotone keys).
// Bitonic warm-start on first batch (R6) avoids the tau=+inf insert flood.

#define NPTS 16384
#define CH 64

#define GLO  (-4.5f)
#define GH   0.28125f          // 9/32
#define INVH 3.5555555556f     // 32/9
#define GDIM 32
#define GCELLS (GDIM * GDIM * GDIM)

typedef __attribute__((ext_vector_type(8))) short short8;
typedef __attribute__((ext_vector_type(4))) float floatx4;

__device__ __forceinline__ unsigned short f2bf(float f) {
    unsigned u = __float_as_uint(f);
    u += 0x7FFFu + ((u >> 16) & 1u);   // RNE
    return (unsigned short)(u >> 16);
}
__device__ __forceinline__ float bf2f(unsigned short u) {
    return __uint_as_float(((unsigned)u) << 16);
}

// 64-bit DPP row_shr:1 (shift within 16-lane DPP rows; lane 0 gets 0).
__device__ __forceinline__ unsigned long long dpp_shr1_u64(unsigned long long x) {
    int lo = (int)(unsigned)(x & 0xFFFFFFFFULL);
    int hi = (int)(unsigned)(x >> 32);
    lo = __builtin_amdgcn_update_dpp(0, lo, 0x111, 0xF, 0xF, false);
    hi = __builtin_amdgcn_update_dpp(0, hi, 0x111, 0xF, 0xF, false);
    return (((unsigned long long)(unsigned)hi) << 32) | (unsigned)lo;
}

__device__ __forceinline__ int cell_of(float x, float y, float z) {
    int cx = (int)floorf((x - GLO) * INVH);
    int cy = (int)floorf((y - GLO) * INVH);
    int cz = (int)floorf((z - GLO) * INVH);
    cx = min(max(cx, 0), GDIM - 1);
    cy = min(max(cy, 0), GDIM - 1);
    cz = min(max(cz, 0), GDIM - 1);
    return (cz * GDIM + cy) * GDIM + cx;
}

// ---------------------------------------------------------------------------
// Grid build
// ---------------------------------------------------------------------------
__global__ __launch_bounds__(256) void zero_kernel(int* __restrict__ counts) {
    counts[blockIdx.x * 256 + threadIdx.x] = 0;
}

__global__ __launch_bounds__(256) void grid_count_kernel(const float* __restrict__ pos,
                                                         int* __restrict__ counts) {
    const int i = blockIdx.x * 256 + threadIdx.x;
    atomicAdd(&counts[cell_of(pos[i * 3], pos[i * 3 + 1], pos[i * 3 + 2])], 1);
}

// starts has GCELLS+1 entries; starts[GCELLS] = NPTS sentinel (run ends).
__global__ __launch_bounds__(1024) void scan_kernel(const int* __restrict__ counts,
                                                    int* __restrict__ starts,
                                                    int* __restrict__ cursor) {
    __shared__ int lds[1024];
    const int t = threadIdx.x;
    int4 v[8];
    const int4* c4 = (const int4*)counts + t * 8;
#pragma unroll
    for (int i = 0; i < 8; ++i) v[i] = c4[i];
    int sum = 0;
#pragma unroll
    for (int i = 0; i < 8; ++i) sum += v[i].x + v[i].y + v[i].z + v[i].w;
    lds[t] = sum;
    __syncthreads();
    for (int off = 1; off < 1024; off <<= 1) {
        int x = 0;
        if (t >= off) x = lds[t - off];
        __syncthreads();
        lds[t] += x;
        __syncthreads();
    }
    int pre = (t == 0) ? 0 : lds[t - 1];
    int4* s4 = (int4*)starts + t * 8;
    int4* u4 = (int4*)cursor + t * 8;
#pragma unroll
    for (int i = 0; i < 8; ++i) {
        int4 o;
        o.x = pre; pre += v[i].x;
        o.y = pre; pre += v[i].y;
        o.z = pre; pre += v[i].z;
        o.w = pre; pre += v[i].w;
        s4[i] = o;
        u4[i] = o;
    }
    if (t == 1023) starts[GCELLS] = pre;   // == NPTS
}

__global__ __launch_bounds__(256) void grid_scatter_kernel(const float* __restrict__ pos,
                                                           int* __restrict__ cursor,
                                                           float4* __restrict__ spos,
                                                           unsigned short* __restrict__ sidx) {
    const int i = blockIdx.x * 256 + threadIdx.x;
    const float a = pos[i * 3], b = pos[i * 3 + 1], c = pos[i * 3 + 2];
    const int dst = atomicAdd(&cursor[cell_of(a, b, c)], 1);
    spos[dst] = make_float4(a, b, c, a * a + b * b + c * c);  // same sq expr as query side
    sidx[dst] = (unsigned short)i;
}

// ---------------------------------------------------------------------------
// Grid KNN search, run-compacted. 1 wave/query. Shell s processed as x-runs
// (contiguous spos segments), enumerated lane-parallel, compacted via wave
// prefix-scan + LDS binary search into dense 64-wide candidate batches.
// Distance = ref formula d = fmaf(-2, dot, sq_i + sq_j) (matches R8 exactly).
// ---------------------------------------------------------------------------
#define SENT 0xFF800000FFFFFFFFULL   // key(+inf) | idx-all-ones

__global__ __launch_bounds__(256) void knn_grid_kernel(const float* __restrict__ pos,
                                                       const float4* __restrict__ spos,
                                                       const unsigned short* __restrict__ sidx,
                                                       const int* __restrict__ starts,
                                                       unsigned short* __restrict__ knn_out) {
    __shared__ int lds_ex[256];
    __shared__ int lds_st[256];
    const int lane  = threadIdx.x & 63;
    const int w     = threadIdx.x >> 6;
    const int lbase = w * 64;
    const int row   = blockIdx.x * 4 + w;

    const float qx = pos[row * 3 + 0];
    const float qy = pos[row * 3 + 1];
    const float qz = pos[row * 3 + 2];
    const float sqi = qx * qx + qy * qy + qz * qz;
    const int cix = min(max((int)floorf((qx - GLO) * INVH), 0), GDIM - 1);
    const int ciy = min(max((int)floorf((qy - GLO) * INVH), 0), GDIM - 1);
    const int ciz = min(max((int)floorf((qz - GLO) * INVH), 0), GDIM - 1);

    unsigned long long list = SENT;
    float tau = __uint_as_float(0x7F800000u);   // +INF
    bool first = true;

    int pax = 1, pbx = 0, pay = 1, pby = 0, paz = 1, pbz = 0;  // empty prev cube

    for (int s = 1; s < GDIM + 1; ++s) {
        const int ax = max(cix - s, 0), bx = min(cix + s, GDIM - 1);
        const int ay = max(ciy - s, 0), by = min(ciy + s, GDIM - 1);
        const int az = max(ciz - s, 0), bz = min(ciz + s, GDIM - 1);
        const int dy = by - ay + 1, dz = bz - az + 1;
        const int npair = dy * dz;
        const float invdy = 1.0f / (float)dy;

        for (int pb = 0; pb < npair; pb += 64) {
            const int pair = pb + lane;
            int stA = 0, lenA = 0, stB = 0, lenB = 0;
            if (pair < npair) {
                const int czo = (int)(((float)pair + 0.5f) * invdy);
                const int cyo = pair - czo * dy;
                const int cy = ay + cyo, cz = az + czo;
                const int rowb = (cz * GDIM + cy) * GDIM;
                const bool inner = cy >= pay && cy <= pby && cz >= paz && cz <= pbz;
                const int bA = inner ? (pax - 1) : bx;
                if (bA >= ax) {
                    stA  = starts[rowb + ax];
                    lenA = starts[rowb + bA + 1] - stA;
                }
                if (inner) {
                    const int aB = pbx + 1;
                    if (bx >= aB) {
                        stB  = starts[rowb + aB];
                        lenB = starts[rowb + bx + 1] - stB;
                    }
                }
            }
#pragma unroll
            for (int setsel = 0; setsel < 2; ++setsel) {
                const int st  = setsel ? stB  : stA;
                const int len = setsel ? lenB : lenA;
                if (__ballot(len > 0) == 0ULL) continue;
                // wave inclusive prefix-scan of run lengths
                unsigned pfx = (unsigned)len;
#pragma unroll
                for (int off = 1; off < 64; off <<= 1) {
                    const unsigned vv = __shfl_up(pfx, off);
                    if (lane >= off) pfx += vv;
                }
                const int T  = __builtin_amdgcn_readlane((int)pfx, 63);
                const int ex = (int)pfx - len;
                lds_ex[lbase + lane] = ex;
                lds_st[lbase + lane] = st;

                for (int b = 0; b < T; b += 64) {
                    const int p = b + lane;
                    int j = 0;
#pragma unroll
                    for (int stp = 32; stp >= 1; stp >>= 1) {
                        const int m = j + stp;
                        if (lds_ex[lbase + m] <= p) j = m;
                    }
                    const int exj = lds_ex[lbase + j];
                    const int stj = lds_st[lbase + j];
                    const bool active = p < T;
                    const int idx = stj + (active ? (p - exj) : 0);
                    const float4 pt = spos[idx];
                    const int jorig = (int)sidx[idx];
                    // reference-formula distance (identical to R8)
                    const float dot = fmaf(qx, pt.x, fmaf(qy, pt.y, qz * pt.z));
                    const float d   = fmaf(-2.0f, dot, sqi + pt.w);

                    if (first) {
                        first = false;
                        unsigned kd = __float_as_uint(d);
                        kd = ((int)kd < 0) ? ~kd : (kd | 0x80000000u);
                        unsigned long long key =
                            (((unsigned long long)kd) << 32) | (unsigned)jorig;
                        if (!(active && jorig != row)) key = SENT;
                        // 64-lane bitonic sort ascending
#pragma unroll
                        for (int k = 2; k <= 64; k <<= 1) {
#pragma unroll
                            for (int jj = k >> 1; jj >= 1; jj >>= 1) {
                                const unsigned long long o = __shfl_xor(key, jj);
                                const bool takeMin =
                                    (((lane & k) == 0) == ((lane & jj) == 0));
                                const unsigned long long mn = (key < o) ? key : o;
                                const unsigned long long mx = (key < o) ? o : key;
                                key = takeMin ? mn : mx;
                            }
                        }
                        list = key;   // lanes 0..15 hold smallest 16, sorted
                        const unsigned thi = (unsigned)__builtin_amdgcn_readlane(
                            (int)(unsigned)(list >> 32), 15);
                        const unsigned fb =
                            (thi >= 0x80000000u) ? (thi & 0x7FFFFFFFu) : ~thi;
                        tau = __uint_as_float(fb);
                        continue;
                    }

                    const bool cand = active && (jorig != row) && (d <= tau);
                    unsigned long long mask = __ballot(cand);
                    if (mask) {
                        unsigned kd = __float_as_uint(d);
                        kd = ((int)kd < 0) ? ~kd : (kd | 0x80000000u);  // monotone
                        do {
                            const int src = __ffsll(mask) - 1;
                            mask &= mask - 1;
                            const unsigned slo = (unsigned)__builtin_amdgcn_readlane(jorig, src);
                            const unsigned shi = (unsigned)__builtin_amdgcn_readlane((int)kd, src);
                            const unsigned long long v =
                                (((unsigned long long)shi) << 32) | slo;
                            const unsigned long long prev = dpp_shr1_u64(list);
                            const unsigned long long lr = list;
                            list = (lr < v) ? lr : ((prev < v) ? v : prev);
                        } while (mask);
                        const unsigned thi = (unsigned)__builtin_amdgcn_readlane(
                            (int)(unsigned)(list >> 32), 15);
                        const unsigned fb =
                            (thi >= 0x80000000u) ? (thi & 0x7FFFFFFFu) : ~thi;
                        tau = __uint_as_float(fb);
                    }
                }
            }
        }

        // termination: min geometric distance from q to unprocessed region,
        // with 1e-4 margin for ref-formula vs geometric rounding skew.
        const float BIG = 1e30f;
        float dout = BIG;
        if (ax > 0)        dout = fminf(dout, qx - (GLO + ax * GH));
        if (bx < GDIM - 1) dout = fminf(dout, (GLO + (bx + 1) * GH) - qx);
        if (ay > 0)        dout = fminf(dout, qy - (GLO + ay * GH));
        if (by < GDIM - 1) dout = fminf(dout, (GLO + (by + 1) * GH) - qy);
        if (az > 0)        dout = fminf(dout, qz - (GLO + az * GH));
        if (bz < GDIM - 1) dout = fminf(dout, (GLO + (bz + 1) * GH) - qz);
        if (dout * dout > tau + 1e-4f) break;
        if (ax == 0 && bx == GDIM - 1 && ay == 0 && by == GDIM - 1 &&
            az == 0 && bz == GDIM - 1) break;
        pax = ax; pbx = bx; pay = ay; pby = by; paz = az; pbz = bz;
    }

    if (lane < 16)
        knn_out[row * 16 + lane] = (unsigned short)(list & 0xFFFFULL);
}

// ---------------------------------------------------------------------------
// prep: v_p = x_p@(W1a - W1b) + b1 -> vout (fp32, == d_out)
//       u_p = x_p@W1b              -> ubuf (bf16)
// Block = 64 points. bf16 MFMA 16x16x32, fp32 accumulate.
// ---------------------------------------------------------------------------
__global__ __launch_bounds__(256) void prep_kernel(const float* __restrict__ x,
                                                   const float* __restrict__ W1,
                                                   const float* __restrict__ b1,
                                                   float* __restrict__ vout,
                                                   unsigned short* __restrict__ ubuf) {
    __shared__ unsigned short Wct[128 * 72];
    __shared__ unsigned short Abuf[64 * 72];
    __shared__ float Wraw[128 * 64];

    const int t    = threadIdx.x;
    const int lane = t & 63;
    const int w    = t >> 6;

    {
        const float4* W1v = (const float4*)W1;
        float4* Wr4 = (float4*)Wraw;
#pragma unroll
        for (int i = 0; i < 8; ++i) Wr4[i * 256 + t] = W1v[i * 256 + t];
    }
    __syncthreads();
    {
        const int n = t & 127;
        const int ks = (t >> 7) * 32;
#pragma unroll
        for (int i = 0; i < 32; ++i) {
            const int k = ks + i;
            float val;
            if (n < 64) val = Wraw[k * 64 + n] - Wraw[(64 + k) * 64 + n];
            else        val = Wraw[(64 + k) * 64 + (n - 64)];
            Wct[n * 72 + k] = f2bf(val);
        }
    }
    {
        const int col = t & 63;
#pragma unroll
        for (int i = 0; i < 16; ++i) {
            const int r2 = (t >> 6) + 4 * i;
            const int gp = blockIdx.x * 64 + r2;
            Abuf[r2 * 72 + col] = f2bf(x[(size_t)gp * CH + col]);
        }
    }
    __syncthreads();

    const int m16 = lane & 15;
    const int q   = lane >> 4;

    floatx4 acc[8];
#pragma unroll
    for (int nt = 0; nt < 8; ++nt) acc[nt] = (floatx4){0.f, 0.f, 0.f, 0.f};

#pragma unroll
    for (int kk = 0; kk < 64; kk += 32) {
        const short8 a = *(const short8*)(Abuf + (w * 16 + m16) * 72 + kk + q * 8);
#pragma unroll
        for (int nt = 0; nt < 8; ++nt) {
            const short8 b = *(const short8*)(Wct + (nt * 16 + m16) * 72 + kk + q * 8);
            acc[nt] = __builtin_amdgcn_mfma_f32_16x16x32_bf16(a, b, acc[nt], 0, 0, 0);
        }
    }

#pragma unroll
    for (int nt = 0; nt < 8; ++nt) {
        const int n = nt * 16 + m16;
#pragma unroll
        for (int r = 0; r < 4; ++r) {
            const int gp = blockIdx.x * 64 + w * 16 + q * 4 + r;
            if (n < 64) vout[(size_t)gp * CH + n] = acc[nt][r] + b1[n];
            else        ubuf[(size_t)gp * CH + (n - 64)] = f2bf(acc[nt][r]);
        }
    }
}

// ---------------------------------------------------------------------------
// edge: block = 8 points (128 edge rows). h = relu(v_i + u_j) staged bf16 in
// LDS; GEMM2 (128x64)@(64x64) via MFMA; max over each point's 16 rows; +b2.
// ---------------------------------------------------------------------------
__global__ __launch_bounds__(256) void edge_kernel(const unsigned short* __restrict__ ubuf,
                                                   const float* __restrict__ W2,
                                                   const float* __restrict__ b2,
                                                   const unsigned short* __restrict__ knn,
                                                   float* __restrict__ out) {
    __shared__ unsigned short h[128 * 72];
    __shared__ unsigned short W2t[64 * 72];

    const int t    = threadIdx.x;
    const int lane = t & 63;
    const int w    = t >> 6;

    {
        const int n = t & 63;
        const int kb = (t >> 6) * 16;
#pragma unroll
        for (int i = 0; i < 16; ++i) {
            const int k = kb + i;
            W2t[n * 72 + k] = f2bf(W2[k * 64 + n]);
        }
    }
    {
        const int k = t >> 4;
        const int c = t & 15;
#pragma unroll
        for (int i = 0; i < 8; ++i) {
            const int gn = blockIdx.x * 8 + i;
            const int gj = (int)knn[gn * 16 + k];
            const float4  vv = ((const float4*)(out + (size_t)gn * CH))[c];
            const ushort4 uu = ((const ushort4*)(ubuf + (size_t)gj * CH))[c];
            ushort4 hv;
            hv.x = f2bf(fmaxf(vv.x + bf2f(uu.x), 0.f));
            hv.y = f2bf(fmaxf(vv.y + bf2f(uu.y), 0.f));
            hv.z = f2bf(fmaxf(vv.z + bf2f(uu.z), 0.f));
            hv.w = f2bf(fmaxf(vv.w + bf2f(uu.w), 0.f));
            const int r2 = i * 16 + k;
            *(ushort4*)(h + r2 * 72 + c * 4) = hv;
        }
    }
    __syncthreads();

    const int m16 = lane & 15;
    const int q   = lane >> 4;

    floatx4 acc[2][4];
#pragma unroll
    for (int i = 0; i < 2; ++i)
#pragma unroll
        for (int nt = 0; nt < 4; ++nt) acc[i][nt] = (floatx4){0.f, 0.f, 0.f, 0.f};

#pragma unroll
    for (int kk = 0; kk < 64; kk += 32) {
        const short8 a0 = *(const short8*)(h + ((w * 2 + 0) * 16 + m16) * 72 + kk + q * 8);
        const short8 a1 = *(const short8*)(h + ((w * 2 + 1) * 16 + m16) * 72 + kk + q * 8);
#pragma unroll
        for (int nt = 0; nt < 4; ++nt) {
            const short8 b = *(const short8*)(W2t + (nt * 16 + m16) * 72 + kk + q * 8);
            acc[0][nt] = __builtin_amdgcn_mfma_f32_16x16x32_bf16(a0, b, acc[0][nt], 0, 0, 0);
            acc[1][nt] = __builtin_amdgcn_mfma_f32_16x16x32_bf16(a1, b, acc[1][nt], 0, 0, 0);
        }
    }

#pragma unroll
    for (int i = 0; i < 2; ++i) {
        const int mt = w * 2 + i;
        const int gn = blockIdx.x * 8 + mt;
#pragma unroll
        for (int nt = 0; nt < 4; ++nt) {
            float m0 = fmaxf(fmaxf(acc[i][nt][0], acc[i][nt][1]),
                             fmaxf(acc[i][nt][2], acc[i][nt][3]));
            m0 = fmaxf(m0, __shfl_xor(m0, 16));
            m0 = fmaxf(m0, __shfl_xor(m0, 32));
            if (lane < 16)
                out[(size_t)gn * CH + nt * 16 + lane] = m0 + b2[nt * 16 + lane];
        }
    }
}

extern "C" void kernel_launch(void* const* d_in, const int* in_sizes, int n_in,
                              void* d_out, int out_size, void* d_ws, size_t ws_size,
                              hipStream_t stream) {
    const float* x   = (const float*)d_in[0];
    const float* pos = (const float*)d_in[1];
    const float* W1  = (const float*)d_in[2];
    const float* b1  = (const float*)d_in[3];
    const float* W2  = (const float*)d_in[4];
    const float* b2  = (const float*)d_in[5];
    float* out = (float*)d_out;

    char* ws = (char*)d_ws;
    unsigned short* knn  = (unsigned short*)ws;                    // 512 KB @ 0
    unsigned short* ubuf = (unsigned short*)(ws + 524288);         // 2 MB
    int*    counts = (int*)(ws + 2621440);                         // 128 KB
    int*    starts = (int*)(ws + 2752512);                         // 128 KB + sentinel
    int*    cursor = (int*)(ws + 2883600);                         // 128 KB
    float4* spos   = (float4*)(ws + 3014672);                      // 256 KB
    unsigned short* sidx = (unsigned short*)(ws + 3276816);        // 32 KB

    zero_kernel<<<GCELLS / 256, 256, 0, stream>>>(counts);
    grid_count_kernel<<<NPTS / 256, 256, 0, stream>>>(pos, counts);
    scan_kernel<<<1, 1024, 0, stream>>>(counts, starts, cursor);
    grid_scatter_kernel<<<NPTS / 256, 256, 0, stream>>>(pos, cursor, spos, sidx);
    knn_grid_kernel<<<NPTS / 4, 256, 0, stream>>>(pos, spos, sidx, starts, knn);
    prep_kernel<<<NPTS / 64, 256, 0, stream>>>(x, W1, b1, out, ubuf);
    edge_kernel<<<NPTS / 8, 256, 0, stream>>>(ubuf, W2, b2, knn, out);
}

// Round 10
// 144.821 us; speedup vs baseline: 2.1791x; 1.0481x over previous
//
#include <hip/hip_runtime.h>
#include <hip/hip_bf16.h>

// EdgeConv: N=16384 points, C=64, D=64, K=16 neighbors. All I/O fp32.
// Pipeline (5 graph nodes):
//   memset(counts) -> [count | prep fused] -> scan -> scatter -> knn -> edge
// R10: (1) zero_kernel -> hipMemsetAsync; prep fused into count kernel
// (independent data; hides prep's ~10us + one launch). (2) knn: NB=4 candidate
// batches in flight -- 4 independent LDS binary searches + batched global
// loads (was 1 serial 6-deep ds_read chain per batch = ~700 cyc exposed).
// (3) knn blocks = 64 thr (1 wave) for tail smoothing. Numerics identical R9.

#define NPTS 16384
#define CH 64

#define GLO  (-4.5f)
#define GH   0.28125f          // 9/32
#define INVH 3.5555555556f     // 32/9
#define GDIM 32
#define GCELLS (GDIM * GDIM * GDIM)

typedef __attribute__((ext_vector_type(8))) short short8;
typedef __attribute__((ext_vector_type(4))) float floatx4;

__device__ __forceinline__ unsigned short f2bf(float f) {
    unsigned u = __float_as_uint(f);
    u += 0x7FFFu + ((u >> 16) & 1u);   // RNE
    return (unsigned short)(u >> 16);
}
__device__ __forceinline__ float bf2f(unsigned short u) {
    return __uint_as_float(((unsigned)u) << 16);
}

// 64-bit DPP row_shr:1 (shift within 16-lane DPP rows; lane 0 gets 0).
__device__ __forceinline__ unsigned long long dpp_shr1_u64(unsigned long long x) {
    int lo = (int)(unsigned)(x & 0xFFFFFFFFULL);
    int hi = (int)(unsigned)(x >> 32);
    lo = __builtin_amdgcn_update_dpp(0, lo, 0x111, 0xF, 0xF, false);
    hi = __builtin_amdgcn_update_dpp(0, hi, 0x111, 0xF, 0xF, false);
    return (((unsigned long long)(unsigned)hi) << 32) | (unsigned)lo;
}

__device__ __forceinline__ int cell_of(float x, float y, float z) {
    int cx = (int)floorf((x - GLO) * INVH);
    int cy = (int)floorf((y - GLO) * INVH);
    int cz = (int)floorf((z - GLO) * INVH);
    cx = min(max(cx, 0), GDIM - 1);
    cy = min(max(cy, 0), GDIM - 1);
    cz = min(max(cz, 0), GDIM - 1);
    return (cz * GDIM + cy) * GDIM + cx;
}

// ---------------------------------------------------------------------------
// Fused: blocks 0..63 = grid count (atomics); blocks 64..319 = prep GEMM
//   prep: v_p = x_p@(W1a-W1b)+b1 -> vout(==d_out) ; u_p = x_p@W1b -> ubuf bf16
// ---------------------------------------------------------------------------
__global__ __launch_bounds__(256) void count_prep_kernel(const float* __restrict__ pos,
                                                         int* __restrict__ counts,
                                                         const float* __restrict__ x,
                                                         const float* __restrict__ W1,
                                                         const float* __restrict__ b1,
                                                         float* __restrict__ vout,
                                                         unsigned short* __restrict__ ubuf) {
    __shared__ unsigned short Wct[128 * 72];
    __shared__ unsigned short Abuf[64 * 72];
    __shared__ float Wraw[128 * 64];

    const int t = threadIdx.x;
    if (blockIdx.x < 64) {
        const int i = blockIdx.x * 256 + t;
        atomicAdd(&counts[cell_of(pos[i * 3], pos[i * 3 + 1], pos[i * 3 + 2])], 1);
        return;
    }
    const int bid  = blockIdx.x - 64;
    const int lane = t & 63;
    const int w    = t >> 6;

    {
        const float4* W1v = (const float4*)W1;
        float4* Wr4 = (float4*)Wraw;
#pragma unroll
        for (int i = 0; i < 8; ++i) Wr4[i * 256 + t] = W1v[i * 256 + t];
    }
    __syncthreads();
    {
        const int n = t & 127;
        const int ks = (t >> 7) * 32;
#pragma unroll
        for (int i = 0; i < 32; ++i) {
            const int k = ks + i;
            float val;
            if (n < 64) val = Wraw[k * 64 + n] - Wraw[(64 + k) * 64 + n];
            else        val = Wraw[(64 + k) * 64 + (n - 64)];
            Wct[n * 72 + k] = f2bf(val);
        }
    }
    {
        const int col = t & 63;
#pragma unroll
        for (int i = 0; i < 16; ++i) {
            const int r2 = (t >> 6) + 4 * i;
            const int gp = bid * 64 + r2;
            Abuf[r2 * 72 + col] = f2bf(x[(size_t)gp * CH + col]);
        }
    }
    __syncthreads();

    const int m16 = lane & 15;
    const int q   = lane >> 4;

    floatx4 acc[8];
#pragma unroll
    for (int nt = 0; nt < 8; ++nt) acc[nt] = (floatx4){0.f, 0.f, 0.f, 0.f};

#pragma unroll
    for (int kk = 0; kk < 64; kk += 32) {
        const short8 a = *(const short8*)(Abuf + (w * 16 + m16) * 72 + kk + q * 8);
#pragma unroll
        for (int nt = 0; nt < 8; ++nt) {
            const short8 b = *(const short8*)(Wct + (nt * 16 + m16) * 72 + kk + q * 8);
            acc[nt] = __builtin_amdgcn_mfma_f32_16x16x32_bf16(a, b, acc[nt], 0, 0, 0);
        }
    }

#pragma unroll
    for (int nt = 0; nt < 8; ++nt) {
        const int n = nt * 16 + m16;
#pragma unroll
        for (int r = 0; r < 4; ++r) {
            const int gp = bid * 64 + w * 16 + q * 4 + r;
            if (n < 64) vout[(size_t)gp * CH + n] = acc[nt][r] + b1[n];
            else        ubuf[(size_t)gp * CH + (n - 64)] = f2bf(acc[nt][r]);
        }
    }
}

// starts has GCELLS+1 entries; starts[GCELLS] = NPTS sentinel (run ends).
__global__ __launch_bounds__(1024) void scan_kernel(const int* __restrict__ counts,
                                                    int* __restrict__ starts,
                                                    int* __restrict__ cursor) {
    __shared__ int lds[1024];
    const int t = threadIdx.x;
    int4 v[8];
    const int4* c4 = (const int4*)counts + t * 8;
#pragma unroll
    for (int i = 0; i < 8; ++i) v[i] = c4[i];
    int sum = 0;
#pragma unroll
    for (int i = 0; i < 8; ++i) sum += v[i].x + v[i].y + v[i].z + v[i].w;
    lds[t] = sum;
    __syncthreads();
    for (int off = 1; off < 1024; off <<= 1) {
        int x = 0;
        if (t >= off) x = lds[t - off];
        __syncthreads();
        lds[t] += x;
        __syncthreads();
    }
    int pre = (t == 0) ? 0 : lds[t - 1];
    int4* s4 = (int4*)starts + t * 8;
    int4* u4 = (int4*)cursor + t * 8;
#pragma unroll
    for (int i = 0; i < 8; ++i) {
        int4 o;
        o.x = pre; pre += v[i].x;
        o.y = pre; pre += v[i].y;
        o.z = pre; pre += v[i].z;
        o.w = pre; pre += v[i].w;
        s4[i] = o;
        u4[i] = o;
    }
    if (t == 1023) starts[GCELLS] = pre;   // == NPTS
}

__global__ __launch_bounds__(256) void grid_scatter_kernel(const float* __restrict__ pos,
                                                           int* __restrict__ cursor,
                                                           float4* __restrict__ spos,
                                                           unsigned short* __restrict__ sidx) {
    const int i = blockIdx.x * 256 + threadIdx.x;
    const float a = pos[i * 3], b = pos[i * 3 + 1], c = pos[i * 3 + 2];
    const int dst = atomicAdd(&cursor[cell_of(a, b, c)], 1);
    spos[dst] = make_float4(a, b, c, a * a + b * b + c * c);  // same sq expr as query side
    sidx[dst] = (unsigned short)i;
}

// ---------------------------------------------------------------------------
// Grid KNN, run-compacted, NB-batched. 1 wave per query (64-thr block).
// Shell s as x-runs (contiguous spos segments); wave prefix-scan; NB=4
// independent LDS binary searches in flight + batched global loads.
// Distance = ref formula d = fmaf(-2, dot, sq_i + sq_j) (identical R8/R9).
// ---------------------------------------------------------------------------
#define SENT 0xFF800000FFFFFFFFULL   // key(+inf) | idx-all-ones
#define NB 4

__global__ __launch_bounds__(64) void knn_grid_kernel(const float* __restrict__ pos,
                                                      const float4* __restrict__ spos,
                                                      const unsigned short* __restrict__ sidx,
                                                      const int* __restrict__ starts,
                                                      unsigned short* __restrict__ knn_out) {
    __shared__ int lds_ex[64];
    __shared__ int lds_st[64];
    const int lane = threadIdx.x;
    const int row  = blockIdx.x;

    const float qx = pos[row * 3 + 0];
    const float qy = pos[row * 3 + 1];
    const float qz = pos[row * 3 + 2];
    const float sqi = qx * qx + qy * qy + qz * qz;
    const int cix = min(max((int)floorf((qx - GLO) * INVH), 0), GDIM - 1);
    const int ciy = min(max((int)floorf((qy - GLO) * INVH), 0), GDIM - 1);
    const int ciz = min(max((int)floorf((qz - GLO) * INVH), 0), GDIM - 1);

    unsigned long long list = SENT;
    float tau = __uint_as_float(0x7F800000u);   // +INF
    bool first = true;

    int pax = 1, pbx = 0, pay = 1, pby = 0, paz = 1, pbz = 0;  // empty prev cube

    for (int s = 1; s < GDIM + 1; ++s) {
        const int ax = max(cix - s, 0), bx = min(cix + s, GDIM - 1);
        const int ay = max(ciy - s, 0), by = min(ciy + s, GDIM - 1);
        const int az = max(ciz - s, 0), bz = min(ciz + s, GDIM - 1);
        const int dy = by - ay + 1, dz = bz - az + 1;
        const int npair = dy * dz;
        const float invdy = 1.0f / (float)dy;

        for (int pb = 0; pb < npair; pb += 64) {
            const int pair = pb + lane;
            int stA = 0, lenA = 0, stB = 0, lenB = 0;
            if (pair < npair) {
                const int czo = (int)(((float)pair + 0.5f) * invdy);
                const int cyo = pair - czo * dy;
                const int cy = ay + cyo, cz = az + czo;
                const int rowb = (cz * GDIM + cy) * GDIM;
                const bool inner = cy >= pay && cy <= pby && cz >= paz && cz <= pbz;
                const int bA = inner ? (pax - 1) : bx;
                if (bA >= ax) {
                    stA  = starts[rowb + ax];
                    lenA = starts[rowb + bA + 1] - stA;
                }
                if (inner) {
                    const int aB = pbx + 1;
                    if (bx >= aB) {
                        stB  = starts[rowb + aB];
                        lenB = starts[rowb + bx + 1] - stB;
                    }
                }
            }
#pragma unroll
            for (int setsel = 0; setsel < 2; ++setsel) {
                const int st  = setsel ? stB  : stA;
                const int len = setsel ? lenB : lenA;
                if (__ballot(len > 0) == 0ULL) continue;
                // wave inclusive prefix-scan of run lengths
                unsigned pfx = (unsigned)len;
#pragma unroll
                for (int off = 1; off < 64; off <<= 1) {
                    const unsigned vv = __shfl_up(pfx, off);
                    if (lane >= off) pfx += vv;
                }
                const int T  = __builtin_amdgcn_readlane((int)pfx, 63);
                lds_ex[lane] = (int)pfx - len;
                lds_st[lane] = st;

                for (int b0 = 0; b0 < T; b0 += 64 * NB) {
                    float4 pts[NB];
                    int    jor[NB];
                    bool   act[NB];
                    bool   live[NB];
#pragma unroll
                    for (int nb = 0; nb < NB; ++nb) {
                        const int bb = b0 + nb * 64;
                        live[nb] = bb < T;           // wave-uniform
                        act[nb] = false;
                        if (live[nb]) {
                            const int p = bb + lane;
                            int j = 0;
#pragma unroll
                            for (int stp = 32; stp >= 1; stp >>= 1) {
                                const int m = j + stp;
                                if (lds_ex[m] <= p) j = m;
                            }
                            int idx = lds_st[j] + (p - lds_ex[j]);
                            idx = min(idx, NPTS - 1);
                            act[nb] = p < T;
                            pts[nb] = spos[idx];
                            jor[nb] = (int)sidx[idx];
                        }
                    }
#pragma unroll
                    for (int nb = 0; nb < NB; ++nb) {
                        if (!live[nb]) continue;
                        // reference-formula distance (identical to R8/R9)
                        const float dot = fmaf(qx, pts[nb].x,
                                               fmaf(qy, pts[nb].y, qz * pts[nb].z));
                        const float d = fmaf(-2.0f, dot, sqi + pts[nb].w);

                        if (first) {
                            first = false;
                            unsigned kd = __float_as_uint(d);
                            kd = ((int)kd < 0) ? ~kd : (kd | 0x80000000u);
                            unsigned long long key =
                                (((unsigned long long)kd) << 32) | (unsigned)jor[nb];
                            if (!(act[nb] && jor[nb] != row)) key = SENT;
                            // 64-lane bitonic sort ascending
#pragma unroll
                            for (int k = 2; k <= 64; k <<= 1) {
#pragma unroll
                                for (int jj = k >> 1; jj >= 1; jj >>= 1) {
                                    const unsigned long long o = __shfl_xor(key, jj);
                                    const bool takeMin =
                                        (((lane & k) == 0) == ((lane & jj) == 0));
                                    const unsigned long long mn = (key < o) ? key : o;
                                    const unsigned long long mx = (key < o) ? o : key;
                                    key = takeMin ? mn : mx;
                                }
                            }
                            list = key;
                            const unsigned thi = (unsigned)__builtin_amdgcn_readlane(
                                (int)(unsigned)(list >> 32), 15);
                            const unsigned fb =
                                (thi >= 0x80000000u) ? (thi & 0x7FFFFFFFu) : ~thi;
                            tau = __uint_as_float(fb);
                            continue;
                        }

                        const bool cand = act[nb] && (jor[nb] != row) && (d <= tau);
                        unsigned long long mask = __ballot(cand);
                        if (mask) {
                            unsigned kd = __float_as_uint(d);
                            kd = ((int)kd < 0) ? ~kd : (kd | 0x80000000u);
                            do {
                                const int src = __ffsll(mask) - 1;
                                mask &= mask - 1;
                                const unsigned slo =
                                    (unsigned)__builtin_amdgcn_readlane(jor[nb], src);
                                const unsigned shi =
                                    (unsigned)__builtin_amdgcn_readlane((int)kd, src);
                                const unsigned long long v =
                                    (((unsigned long long)shi) << 32) | slo;
                                const unsigned long long prev = dpp_shr1_u64(list);
                                const unsigned long long lr = list;
                                list = (lr < v) ? lr : ((prev < v) ? v : prev);
                            } while (mask);
                            const unsigned thi = (unsigned)__builtin_amdgcn_readlane(
                                (int)(unsigned)(list >> 32), 15);
                            const unsigned fb =
                                (thi >= 0x80000000u) ? (thi & 0x7FFFFFFFu) : ~thi;
                            tau = __uint_as_float(fb);
                        }
                    }
                }
            }
        }

        // termination: min geometric distance from q to unprocessed region,
        // with 1e-4 margin for ref-formula vs geometric rounding skew.
        const float BIG = 1e30f;
        float dout = BIG;
        if (ax > 0)        dout = fminf(dout, qx - (GLO + ax * GH));
        if (bx < GDIM - 1) dout = fminf(dout, (GLO + (bx + 1) * GH) - qx);
        if (ay > 0)        dout = fminf(dout, qy - (GLO + ay * GH));
        if (by < GDIM - 1) dout = fminf(dout, (GLO + (by + 1) * GH) - qy);
        if (az > 0)        dout = fminf(dout, qz - (GLO + az * GH));
        if (bz < GDIM - 1) dout = fminf(dout, (GLO + (bz + 1) * GH) - qz);
        if (dout * dout > tau + 1e-4f) break;
        if (ax == 0 && bx == GDIM - 1 && ay == 0 && by == GDIM - 1 &&
            az == 0 && bz == GDIM - 1) break;
        pax = ax; pbx = bx; pay = ay; pby = by; paz = az; pbz = bz;
    }

    if (lane < 16)
        knn_out[row * 16 + lane] = (unsigned short)(list & 0xFFFFULL);
}

// ---------------------------------------------------------------------------
// edge: block = 8 points (128 edge rows). h = relu(v_i + u_j) staged bf16 in
// LDS; GEMM2 (128x64)@(64x64) via MFMA; max over each point's 16 rows; +b2.
// ---------------------------------------------------------------------------
__global__ __launch_bounds__(256) void edge_kernel(const unsigned short* __restrict__ ubuf,
                                                   const float* __restrict__ W2,
                                                   const float* __restrict__ b2,
                                                   const unsigned short* __restrict__ knn,
                                                   float* __restrict__ out) {
    __shared__ unsigned short h[128 * 72];
    __shared__ unsigned short W2t[64 * 72];

    const int t    = threadIdx.x;
    const int lane = t & 63;
    const int w    = t >> 6;

    {
        const int n = t & 63;
        const int kb = (t >> 6) * 16;
#pragma unroll
        for (int i = 0; i < 16; ++i) {
            const int k = kb + i;
            W2t[n * 72 + k] = f2bf(W2[k * 64 + n]);
        }
    }
    {
        const int k = t >> 4;
        const int c = t & 15;
#pragma unroll
        for (int i = 0; i < 8; ++i) {
            const int gn = blockIdx.x * 8 + i;
            const int gj = (int)knn[gn * 16 + k];
            const float4  vv = ((const float4*)(out + (size_t)gn * CH))[c];
            const ushort4 uu = ((const ushort4*)(ubuf + (size_t)gj * CH))[c];
            ushort4 hv;
            hv.x = f2bf(fmaxf(vv.x + bf2f(uu.x), 0.f));
            hv.y = f2bf(fmaxf(vv.y + bf2f(uu.y), 0.f));
            hv.z = f2bf(fmaxf(vv.z + bf2f(uu.z), 0.f));
            hv.w = f2bf(fmaxf(vv.w + bf2f(uu.w), 0.f));
            const int r2 = i * 16 + k;
            *(ushort4*)(h + r2 * 72 + c * 4) = hv;
        }
    }
    __syncthreads();

    const int m16 = lane & 15;
    const int q   = lane >> 4;

    floatx4 acc[2][4];
#pragma unroll
    for (int i = 0; i < 2; ++i)
#pragma unroll
        for (int nt = 0; nt < 4; ++nt) acc[i][nt] = (floatx4){0.f, 0.f, 0.f, 0.f};

#pragma unroll
    for (int kk = 0; kk < 64; kk += 32) {
        const short8 a0 = *(const short8*)(h + ((w * 2 + 0) * 16 + m16) * 72 + kk + q * 8);
        const short8 a1 = *(const short8*)(h + ((w * 2 + 1) * 16 + m16) * 72 + kk + q * 8);
#pragma unroll
        for (int nt = 0; nt < 4; ++nt) {
            const short8 b = *(const short8*)(W2t + (nt * 16 + m16) * 72 + kk + q * 8);
            acc[0][nt] = __builtin_amdgcn_mfma_f32_16x16x32_bf16(a0, b, acc[0][nt], 0, 0, 0);
            acc[1][nt] = __builtin_amdgcn_mfma_f32_16x16x32_bf16(a1, b, acc[1][nt], 0, 0, 0);
        }
    }

#pragma unroll
    for (int i = 0; i < 2; ++i) {
        const int mt = w * 2 + i;
        const int gn = blockIdx.x * 8 + mt;
#pragma unroll
        for (int nt = 0; nt < 4; ++nt) {
            float m0 = fmaxf(fmaxf(acc[i][nt][0], acc[i][nt][1]),
                             fmaxf(acc[i][nt][2], acc[i][nt][3]));
            m0 = fmaxf(m0, __shfl_xor(m0, 16));
            m0 = fmaxf(m0, __shfl_xor(m0, 32));
            if (lane < 16)
                out[(size_t)gn * CH + nt * 16 + lane] = m0 + b2[nt * 16 + lane];
        }
    }
}

extern "C" void kernel_launch(void* const* d_in, const int* in_sizes, int n_in,
                              void* d_out, int out_size, void* d_ws, size_t ws_size,
                              hipStream_t stream) {
    const float* x   = (const float*)d_in[0];
    const float* pos = (const float*)d_in[1];
    const float* W1  = (const float*)d_in[2];
    const float* b1  = (const float*)d_in[3];
    const float* W2  = (const float*)d_in[4];
    const float* b2  = (const float*)d_in[5];
    float* out = (float*)d_out;

    char* ws = (char*)d_ws;
    unsigned short* knn  = (unsigned short*)ws;                    // 512 KB @ 0
    unsigned short* ubuf = (unsigned short*)(ws + 524288);         // 2 MB
    int*    counts = (int*)(ws + 2621440);                         // 128 KB
    int*    starts = (int*)(ws + 2752512);                         // 128 KB + sentinel
    int*    cursor = (int*)(ws + 2883600);                         // 128 KB
    float4* spos   = (float4*)(ws + 3014672);                      // 256 KB
    unsigned short* sidx = (unsigned short*)(ws + 3276816);        // 32 KB

    hipMemsetAsync(counts, 0, GCELLS * sizeof(int), stream);
    count_prep_kernel<<<320, 256, 0, stream>>>(pos, counts, x, W1, b1, out, ubuf);
    scan_kernel<<<1, 1024, 0, stream>>>(counts, starts, cursor);
    grid_scatter_kernel<<<NPTS / 256, 256, 0, stream>>>(pos, cursor, spos, sidx);
    knn_grid_kernel<<<NPTS, 64, 0, stream>>>(pos, spos, sidx, starts, knn);
    edge_kernel<<<NPTS / 8, 256, 0, stream>>>(ubuf, W2, b2, knn, out);
}